// Round 18
// baseline (196.165 us; speedup 1.0000x reference)
//
#include <hip/hip_runtime.h>

#define TT 12
#define DD 96
#define WW 96
#define PLANE (DD*WW)      // 9216
#define SP (TT*PLANE)      // 110592
#define F 64

typedef short bf16x8 __attribute__((ext_vector_type(8)));
typedef short bf16x4 __attribute__((ext_vector_type(4)));
typedef float f32x4  __attribute__((ext_vector_type(4)));

__device__ __forceinline__ float sigmoidf_fast(float x){
    return 1.0f / (1.0f + __expf(-x));
}
// tanh = 1 - 2/(e^{2x}+1): 5 ops, clamp-free (x->+inf: e=inf -> 1; x->-inf: -1)
__device__ __forceinline__ float tanhf_fast(float x){
    const float e = __expf(2.0f * x);
    return 1.0f - 2.0f / (e + 1.0f);
}
__device__ __forceinline__ unsigned short f2bf(float x){
    unsigned int u = __float_as_uint(x);
    u = (u + 0x7FFFu + ((u >> 16) & 1u)) >> 16;   // RNE
    return (unsigned short)u;
}
__device__ __forceinline__ float bf2f(unsigned short u){
    return __uint_as_float(((unsigned int)u) << 16);
}
__device__ __forceinline__ unsigned int cvt_pk_bf16(float lo, float hi){
    unsigned int r;
    asm("v_cvt_pk_bf16_f32 %0, %1, %2" : "=v"(r) : "v"(lo), "v"(hi));
    return r;
}

// ===========================================================================
// PREP: all weight repacks (200704 elems) + transpose h1 -> hT.
// blocks [0,784): repack flat; blocks [784, 784+1728): transpose tiles.
// ===========================================================================
__device__ __forceinline__ unsigned short repack_lru_elem(
    const float* wih, const float* whh, int idx)
{
    const int j    = idx & 7;
    const int lane = (idx >> 3) & 63;
    const int frag = idx >> 9;
    const int ks   = frag & 1;
    const int t    = (frag >> 1) % 12;
    const int fhi  = frag / 24;
    const int g    = (t < 6) ? t : t - 6;
    const int m    = g * 64 + fhi * 16 + (lane & 15);
    const int kk   = ks * 32 + (lane >> 4) * 8 + j;
    const float v  = (t < 6) ? wih[m * F + kk] : whh[m * F + kk];
    return f2bf(v);
}
__device__ __forceinline__ unsigned short repack_sp_elem(
    const float* wgt, int idx)
{
    const int j    = idx & 7;
    const int lane = (idx >> 3) & 63;
    const int frag = idx >> 9;
    const int fhi  = frag & 3;
    const int cl   = (frag >> 2) & 1;
    const int tap  = frag >> 3;
    const int f    = fhi * 16 + (lane & 15);
    const int c    = cl * 32 + (lane >> 4) * 8 + j;
    return f2bf(wgt[(f * 64 + c) * 9 + tap]);
}
__device__ __forceinline__ unsigned short repack_tm_elem(
    const float* wgt, int idx)
{
    const int j    = idx & 7;
    const int lane = (idx >> 3) & 63;
    const int frag = idx >> 9;
    const int fhi  = frag & 3;
    const int cl   = (frag >> 2) & 1;
    const int dt   = frag >> 3;
    const int f    = fhi * 16 + (lane & 15);
    const int c    = cl * 32 + (lane >> 4) * 8 + j;
    return f2bf(wgt[(f * 64 + c) * 3 + dt]);
}

__global__ __launch_bounds__(256) void prep_all(
    const float* __restrict__ r1_wih, const float* __restrict__ r1_whh,
    const float* __restrict__ r2_wih, const float* __restrict__ r2_whh,
    const float* __restrict__ wbt_w1, const float* __restrict__ wout_w1,
    const float* __restrict__ win_w2, const float* __restrict__ wbt_w2,
    const float* __restrict__ win_w1, const float* __restrict__ h1,
    unsigned short* __restrict__ lru1_awp, unsigned short* __restrict__ lru2_awp,
    unsigned short* __restrict__ wbt1_f, unsigned short* __restrict__ wout1_f,
    unsigned short* __restrict__ win2_f, unsigned short* __restrict__ wbt2_f,
    unsigned short* __restrict__ win1_awp, unsigned short* __restrict__ hT)
{
    __shared__ float tile[64 * 65];
    const int bx = blockIdx.x;
    if (bx < 784) {
        const int idx = bx * 256 + threadIdx.x;
        if (idx < 49152) {
            lru1_awp[idx] = repack_lru_elem(r1_wih, r1_whh, idx);
        } else if (idx < 98304) {
            const int i = idx - 49152;
            lru2_awp[i] = repack_lru_elem(r2_wih, r2_whh, i);
        } else if (idx < 135168) {
            const int i = idx - 98304;
            wbt1_f[i] = repack_sp_elem(wbt_w1, i);
        } else if (idx < 172032) {
            const int i = idx - 135168;
            wout1_f[i] = repack_sp_elem(wout_w1, i);
        } else if (idx < 184320) {
            const int i = idx - 172032;
            win2_f[i] = repack_tm_elem(win_w2, i);
        } else if (idx < 196608) {
            const int i = idx - 184320;
            wbt2_f[i] = repack_tm_elem(wbt_w2, i);
        } else if (idx < 200704) {
            // win1 im2col A-frags: frag = fhi*2+ks; k = c*16+tap (tap 9..15 pad 0)
            const int i    = idx - 196608;
            const int j    = i & 7;
            const int lane = (i >> 3) & 63;
            const int frag = i >> 9;          // 0..7
            const int ks   = frag & 1;
            const int fhi  = frag >> 1;
            const int m    = fhi * 16 + (lane & 15);
            const int kk   = ks * 32 + (lane >> 4) * 8 + j;
            const int c    = kk >> 4;
            const int tp   = kk & 15;
            win1_awp[i] = (tp < 9) ? f2bf(win_w1[(m * 4 + c) * 9 + tp])
                                   : (unsigned short)0;
        }
    } else {
        // transpose h1 tile (256 threads)
        const int tid  = threadIdx.x;
        const int wv   = tid >> 6;
        const int lane = tid & 63;
        const int p0   = (bx - 784) * 64;
        #pragma unroll
        for (int cc = 0; cc < 16; cc++) {
            const int c = cc * 4 + wv;
            tile[lane * 65 + c] = h1[(size_t)c * SP + p0 + lane];
        }
        __syncthreads();
        #pragma unroll
        for (int k = 0; k < 2; k++) {
            const int p  = (tid >> 3) + k * 32;
            const int c0 = (tid & 7) * 8;
            bf16x8 v;
            #pragma unroll
            for (int i = 0; i < 8; i++)
                v[i] = (short)f2bf(tile[p * 65 + c0 + i]);
            *(bf16x8*)(hT + (size_t)(p0 + p) * 64 + c0) = v;
        }
    }
}

// ===========================================================================
// FUSED win stage: im2col MFMA spatial conv (CIN=4, K=64 padded) -> LDS
// (swizzled bf16) -> temporal tm MFMA (weights LDS-staged) -> bufB.
// ===========================================================================
__global__ __launch_bounds__(512, 4) void fused_win(
    const float* __restrict__ x,
    const unsigned short* __restrict__ awp1, const float* __restrict__ bias1,
    const unsigned short* __restrict__ afr_tm, const float* __restrict__ bias_tm,
    unsigned short* __restrict__ out)
{
    __shared__ unsigned short y[8 * 2048];     // 32 KB
    __shared__ unsigned short wbuf[12288];     // 24 KB
    const int tid  = threadIdx.x;
    const int wv   = tid >> 6;
    const int lane = tid & 63;
    const int col  = lane & 15;
    const int kg   = lane >> 4;
    const int bx   = blockIdx.x;             // 0..575
    const int th   = bx / 288;
    const int rem  = bx - th * 288;
    const int d    = rem / 3;
    const int wseg = rem - d * 3;
    const int w0   = wseg * 32;
    const int t0   = th * 6;
    const int tsrc = (t0 + wv + 11) % 12;

    // stage tm weight table (24 KB) early -- used in phase B
    {
        const uint4* src = (const uint4*)afr_tm;
        uint4* dst = (uint4*)wbuf;
        #pragma unroll
        for (int i = 0; i < 3; i++)
            dst[i * 512 + tid] = src[i * 512 + tid];
    }

    // ---- phase A: spatial conv via im2col MFMA ----
    const int kgodd = kg & 1;
    const int c_lo  = kg >> 1;
    int wn[2];
    wn[0] = w0 + col;
    wn[1] = w0 + 16 + col;

    bf16x8 bf[2][2];
    const float* xb = x + (size_t)tsrc * PLANE;
    #pragma unroll
    for (int ks = 0; ks < 2; ks++) {
        const int c = ks * 2 + c_lo;
        const float* xc = xb + (size_t)c * SP;
        #pragma unroll
        for (int nt = 0; nt < 2; nt++) {
            bf16x8 v;
            #pragma unroll
            for (int j = 0; j < 8; j++) v[j] = 0;
            if (!kgodd) {
                #pragma unroll
                for (int j = 0; j < 8; j++) {   // tp = j = ddi*3+dwi
                    const int ddi = j / 3, dwi = j % 3;
                    const int dr = min(max(d + ddi - 1, 0), DD - 1);
                    const int wc = min(max(wn[nt] + dwi - 1, 0), WW - 1);
                    v[j] = (short)f2bf(xc[dr * WW + wc]);
                }
            } else {                             // tp = 8: ddi=2, dwi=2
                const int dr = min(d + 1, DD - 1);
                const int wc = min(wn[nt] + 1, WW - 1);
                v[0] = (short)f2bf(xc[dr * WW + wc]);
            }
            bf[ks][nt] = v;
        }
    }

    f32x4 acc[4][2];
    #pragma unroll
    for (int fhi = 0; fhi < 4; fhi++)
        #pragma unroll
        for (int nt = 0; nt < 2; nt++)
            acc[fhi][nt] = (f32x4){0.f, 0.f, 0.f, 0.f};

    #pragma unroll
    for (int ks = 0; ks < 2; ks++) {
        #pragma unroll
        for (int fhi = 0; fhi < 4; fhi++) {
            const bf16x8 a = *(const bf16x8*)(awp1 + (size_t)(fhi * 2 + ks) * 512 + lane * 8);
            acc[fhi][0] = __builtin_amdgcn_mfma_f32_16x16x32_bf16(a, bf[ks][0], acc[fhi][0], 0, 0, 0);
            acc[fhi][1] = __builtin_amdgcn_mfma_f32_16x16x32_bf16(a, bf[ks][1], acc[fhi][1], 0, 0, 0);
        }
    }

    // epilogue -> LDS (swizzled), bias + relu
    #pragma unroll
    for (int fhi = 0; fhi < 4; fhi++) {
        const float4 bv = *(const float4*)(bias1 + fhi * 16 + kg * 4);
        const int f0 = fhi * 16 + kg * 4;
        #pragma unroll
        for (int nt = 0; nt < 2; nt++) {
            const int pl = nt * 16 + col;
            const unsigned int lo = cvt_pk_bf16(fmaxf(acc[fhi][nt][0] + bv.x, 0.f),
                                                fmaxf(acc[fhi][nt][1] + bv.y, 0.f));
            const unsigned int hi = cvt_pk_bf16(fmaxf(acc[fhi][nt][2] + bv.z, 0.f),
                                                fmaxf(acc[fhi][nt][3] + bv.w, 0.f));
            const int idx = wv * 2048 + pl * 64 + (f0 ^ ((pl & 7) << 3));
            *(uint2*)(y + idx) = make_uint2(lo, hi);
        }
    }

    __syncthreads();

    // ---- phase B: temporal conv (waves 0..5), weights from wbuf ----
    if (wv < 6) {
        f32x4 acc2[4][2];
        #pragma unroll
        for (int fhi = 0; fhi < 4; fhi++)
            #pragma unroll
            for (int nt = 0; nt < 2; nt++)
                acc2[fhi][nt] = (f32x4){0.f, 0.f, 0.f, 0.f};

        const int cswz = (col & 7) << 3;
        const int lane8 = lane * 8;
        #pragma unroll
        for (int dt = 0; dt < 3; dt++) {
            const unsigned short* yb = y + (wv + dt) * 2048;
            #pragma unroll
            for (int cl = 0; cl < 2; cl++) {
                const int coff = (cl * 32 + kg * 8) ^ cswz;
                const bf16x8 b0 = *(const bf16x8*)(yb + col * 64 + coff);
                const bf16x8 b1 = *(const bf16x8*)(yb + (col + 16) * 64 + coff);
                const unsigned short* ap = wbuf + ((dt * 2 + cl) * 4) * 512 + lane8;
                #pragma unroll
                for (int fhi = 0; fhi < 4; fhi++) {
                    const bf16x8 a = *(const bf16x8*)(ap + fhi * 512);
                    acc2[fhi][0] = __builtin_amdgcn_mfma_f32_16x16x32_bf16(a, b0, acc2[fhi][0], 0, 0, 0);
                    acc2[fhi][1] = __builtin_amdgcn_mfma_f32_16x16x32_bf16(a, b1, acc2[fhi][1], 0, 0, 0);
                }
            }
        }

        const int pbase = (t0 + wv) * PLANE + d * WW + w0;
        #pragma unroll
        for (int fhi = 0; fhi < 4; fhi++) {
            const float4 bv = *(const float4*)(bias_tm + fhi * 16 + kg * 4);
            #pragma unroll
            for (int nt = 0; nt < 2; nt++) {
                const int p = pbase + nt * 16 + col;
                const unsigned int lo = cvt_pk_bf16(fmaxf(acc2[fhi][nt][0] + bv.x, 0.f),
                                                    fmaxf(acc2[fhi][nt][1] + bv.y, 0.f));
                const unsigned int hi = cvt_pk_bf16(fmaxf(acc2[fhi][nt][2] + bv.z, 0.f),
                                                    fmaxf(acc2[fhi][nt][3] + bv.w, 0.f));
                *(uint2*)(out + (size_t)p * 64 + fhi * 16 + kg * 4) = make_uint2(lo, hi);
            }
        }
    }
}

// ===========================================================================
// Shared phase A for the 64-channel spatial conv (wbt/wout), MFMA, -> LDS.
// Per-ddi-row LDS staging of the sp weight table (24 KB slices into wbuf).
// Must be called by ALL threads of the block (contains barriers).
// ===========================================================================
__device__ __forceinline__ void fused_phaseA_sp(
    const unsigned short* __restrict__ in,
    const unsigned short* __restrict__ afr_sp, const float* __restrict__ bias_sp,
    unsigned short* __restrict__ y, unsigned short* __restrict__ wbuf,
    int tid, int wv, int col, int kg, int d, int w0, int t)
{
    int wn[2];
    wn[0] = w0 + col;
    wn[1] = w0 + 16 + col;
    int voff[2][3];
    #pragma unroll
    for (int nt = 0; nt < 2; nt++)
        #pragma unroll
        for (int dwi = 0; dwi < 3; dwi++) {
            int wc = wn[nt] + dwi - 1;
            wc = min(max(wc, 0), WW - 1);
            voff[nt][dwi] = wc * 64 + kg * 8;
        }

    f32x4 acc[4][2];
    #pragma unroll
    for (int fhi = 0; fhi < 4; fhi++)
        #pragma unroll
        for (int nt = 0; nt < 2; nt++)
            acc[fhi][nt] = (f32x4){0.f, 0.f, 0.f, 0.f};

    const int tb = t * PLANE;
    const int lane8 = (kg * 16 + col) * 8;
    #pragma unroll
    for (int ddi = 0; ddi < 3; ddi++) {
        __syncthreads();   // previous row's wbuf reads complete
        {
            const uint4* src = (const uint4*)(afr_sp + (size_t)ddi * 12288);
            uint4* dst = (uint4*)wbuf;
            #pragma unroll
            for (int i = 0; i < 3; i++)
                dst[i * 512 + tid] = src[i * 512 + tid];
        }
        __syncthreads();

        int dr = d + ddi - 1;
        dr = min(max(dr, 0), DD - 1);
        const unsigned short* rp = in + (size_t)(tb + dr * WW) * 64;

        bf16x8 row[3][2][2];   // [dwi][cl][nt]
        #pragma unroll
        for (int dwi = 0; dwi < 3; dwi++)
            #pragma unroll
            for (int cl = 0; cl < 2; cl++) {
                row[dwi][cl][0] = *(const bf16x8*)(rp + voff[0][dwi] + cl * 32);
                row[dwi][cl][1] = *(const bf16x8*)(rp + voff[1][dwi] + cl * 32);
            }

        #pragma unroll
        for (int dwi = 0; dwi < 3; dwi++) {
            #pragma unroll
            for (int cl = 0; cl < 2; cl++) {
                const unsigned short* ap = wbuf + ((dwi * 2 + cl) * 4) * 512 + lane8;
                #pragma unroll
                for (int fhi = 0; fhi < 4; fhi++) {
                    const bf16x8 a = *(const bf16x8*)(ap + fhi * 512);
                    acc[fhi][0] = __builtin_amdgcn_mfma_f32_16x16x32_bf16(a, row[dwi][cl][0], acc[fhi][0], 0, 0, 0);
                    acc[fhi][1] = __builtin_amdgcn_mfma_f32_16x16x32_bf16(a, row[dwi][cl][1], acc[fhi][1], 0, 0, 0);
                }
            }
        }
    }

    #pragma unroll
    for (int fhi = 0; fhi < 4; fhi++) {
        const float4 bv = *(const float4*)(bias_sp + fhi * 16 + kg * 4);
        const int f0 = fhi * 16 + kg * 4;
        #pragma unroll
        for (int nt = 0; nt < 2; nt++) {
            const int pl = nt * 16 + col;
            const unsigned int lo = cvt_pk_bf16(fmaxf(acc[fhi][nt][0] + bv.x, 0.f),
                                                fmaxf(acc[fhi][nt][1] + bv.y, 0.f));
            const unsigned int hi = cvt_pk_bf16(fmaxf(acc[fhi][nt][2] + bv.z, 0.f),
                                                fmaxf(acc[fhi][nt][3] + bv.w, 0.f));
            const int idx = wv * 2048 + pl * 64 + (f0 ^ ((pl & 7) << 3));
            *(uint2*)(y + idx) = make_uint2(lo, hi);
        }
    }
}

// ===========================================================================
// FUSED wbt: spatial->LDS->temporal (blocks <576) + transpose h2 rider
// (blocks >=576, reuses hT which is dead after lru1).
// ===========================================================================
__global__ __launch_bounds__(512, 4) void fused_sp_tm_tr(
    const unsigned short* __restrict__ in,
    const unsigned short* __restrict__ afr_sp, const float* __restrict__ bias_sp,
    const unsigned short* __restrict__ afr_tm, const float* __restrict__ bias_tm,
    unsigned short* __restrict__ out,
    const float* __restrict__ h2, unsigned short* __restrict__ hT)
{
    __shared__ unsigned short y[8 * 2048];     // 32 KB (aliased by transpose)
    __shared__ unsigned short wbuf[12288];     // 24 KB weight staging
    const int tid  = threadIdx.x;
    const int wv   = tid >> 6;
    const int lane = tid & 63;
    const int bx   = blockIdx.x;

    if (bx >= 576) {
        // ---- transpose h2 tile: f32 [c][p] -> bf16 [p][c] ----
        float* tile = (float*)y;             // 64*65*4 = 16.6 KB < 32 KB
        const int p0 = (bx - 576) * 64;
        #pragma unroll
        for (int cc = 0; cc < 8; cc++) {
            const int c = cc * 8 + wv;
            tile[lane * 65 + c] = h2[(size_t)c * SP + p0 + lane];
        }
        __syncthreads();
        const int p  = tid >> 3;
        const int c0 = (tid & 7) * 8;
        bf16x8 v;
        #pragma unroll
        for (int i = 0; i < 8; i++)
            v[i] = (short)f2bf(tile[p * 65 + c0 + i]);
        *(bf16x8*)(hT + (size_t)(p0 + p) * 64 + c0) = v;
        return;
    }

    const int col  = lane & 15;
    const int kg   = lane >> 4;
    const int th   = bx / 288;
    const int rem  = bx - th * 288;
    const int d    = rem / 3;
    const int wseg = rem - d * 3;
    const int w0   = wseg * 32;
    const int t0   = th * 6;

    fused_phaseA_sp(in, afr_sp, bias_sp, y, wbuf, tid, wv, col, kg, d, w0,
                    (t0 + wv + 11) % 12);

    // restage wbuf with tm table; barrier also publishes y
    __syncthreads();
    {
        const uint4* src = (const uint4*)afr_tm;
        uint4* dst = (uint4*)wbuf;
        #pragma unroll
        for (int i = 0; i < 3; i++)
            dst[i * 512 + tid] = src[i * 512 + tid];
    }
    __syncthreads();

    if (wv < 6) {
        f32x4 acc[4][2];
        #pragma unroll
        for (int fhi = 0; fhi < 4; fhi++)
            #pragma unroll
            for (int nt = 0; nt < 2; nt++)
                acc[fhi][nt] = (f32x4){0.f, 0.f, 0.f, 0.f};

        const int cswz = (col & 7) << 3;
        const int lane8 = lane * 8;
        #pragma unroll
        for (int dt = 0; dt < 3; dt++) {
            const unsigned short* yb = y + (wv + dt) * 2048;
            #pragma unroll
            for (int cl = 0; cl < 2; cl++) {
                const int coff = (cl * 32 + kg * 8) ^ cswz;
                const bf16x8 b0 = *(const bf16x8*)(yb + col * 64 + coff);
                const bf16x8 b1 = *(const bf16x8*)(yb + (col + 16) * 64 + coff);
                const unsigned short* ap = wbuf + ((dt * 2 + cl) * 4) * 512 + lane8;
                #pragma unroll
                for (int fhi = 0; fhi < 4; fhi++) {
                    const bf16x8 a = *(const bf16x8*)(ap + fhi * 512);
                    acc[fhi][0] = __builtin_amdgcn_mfma_f32_16x16x32_bf16(a, b0, acc[fhi][0], 0, 0, 0);
                    acc[fhi][1] = __builtin_amdgcn_mfma_f32_16x16x32_bf16(a, b1, acc[fhi][1], 0, 0, 0);
                }
            }
        }

        const int pbase = (t0 + wv) * PLANE + d * WW + w0;
        #pragma unroll
        for (int fhi = 0; fhi < 4; fhi++) {
            const float4 bv = *(const float4*)(bias_tm + fhi * 16 + kg * 4);
            #pragma unroll
            for (int nt = 0; nt < 2; nt++) {
                const int p = pbase + nt * 16 + col;
                const unsigned int lo = cvt_pk_bf16(fmaxf(acc[fhi][nt][0] + bv.x, 0.f),
                                                    fmaxf(acc[fhi][nt][1] + bv.y, 0.f));
                const unsigned int hi = cvt_pk_bf16(fmaxf(acc[fhi][nt][2] + bv.z, 0.f),
                                                    fmaxf(acc[fhi][nt][3] + bv.w, 0.f));
                *(uint2*)(out + (size_t)p * 64 + fhi * 16 + kg * 4) = make_uint2(lo, hi);
            }
        }
    }
}

// ===========================================================================
// FUSED wout: spatial->LDS->final temporal (COUT=2, no relu, f32 out).
// ===========================================================================
__global__ __launch_bounds__(512, 4) void fused_sp_tmout(
    const unsigned short* __restrict__ in,
    const unsigned short* __restrict__ afr_sp, const float* __restrict__ bias_sp,
    const float* __restrict__ wgt, const float* __restrict__ bias_out,
    float* __restrict__ out)
{
    __shared__ unsigned short y[8 * 2048];     // 32 KB
    __shared__ unsigned short wbuf[12288];     // 24 KB weight staging
    const int tid  = threadIdx.x;
    const int wv   = tid >> 6;
    const int lane = tid & 63;
    const int col  = lane & 15;
    const int kg   = lane >> 4;
    const int bx   = blockIdx.x;
    const int th   = bx / 288;
    const int rem  = bx - th * 288;
    const int d    = rem / 3;
    const int wseg = rem - d * 3;
    const int w0   = wseg * 32;
    const int t0   = th * 6;

    fused_phaseA_sp(in, afr_sp, bias_sp, y, wbuf, tid, wv, col, kg, d, w0,
                    (t0 + wv + 11) % 12);
    __syncthreads();

    if (tid < 384) {
        const int pl = tid & 31;
        const int tv = (tid >> 5) % 6;
        const int ch = tid / 192;            // wave-uniform
        const int cswz = (pl & 7) << 3;
        float acc = 0.f;
        #pragma unroll
        for (int c0 = 0; c0 < 64; c0 += 8) {
            const int coff = pl * 64 + (c0 ^ cswz);
            const bf16x8 vm = *(const bf16x8*)(y + (tv    ) * 2048 + coff);
            const bf16x8 vc = *(const bf16x8*)(y + (tv + 1) * 2048 + coff);
            const bf16x8 vp = *(const bf16x8*)(y + (tv + 2) * 2048 + coff);
            #pragma unroll
            for (int jj = 0; jj < 8; jj++) {
                const int c = c0 + jj;
                const float* wq = wgt + (ch * 64 + c) * 3;
                acc += bf2f((unsigned short)vm[jj]) * wq[0]
                     + bf2f((unsigned short)vc[jj]) * wq[1]
                     + bf2f((unsigned short)vp[jj]) * wq[2];
            }
        }
        const int p = (t0 + tv) * PLANE + d * WW + w0 + pl;
        out[ch * SP + p] = acc + bias_out[ch];
    }
}

// ===========================================================================
// LRU via MFMA, v8: v7 (LDS-staged weight pair, 8 waves/block) with the
// f32 h epilogue read replaced by bf16 hT reads (L2-hit scatters; round-6
// verified numerics) and a cheaper 5-op tanh + fma blends.
// ===========================================================================
__global__ __launch_bounds__(512, 2) void lru_mfma8(
    const unsigned short* __restrict__ x, const unsigned short* __restrict__ hT,
    const unsigned short* __restrict__ awp,
    const float* __restrict__ bih, const float* __restrict__ bh,
    unsigned short* __restrict__ out, float* __restrict__ hnew)
{
    __shared__ unsigned short sA[24576];   // 48 KB: awp slice for fhi pair
    const int tid  = threadIdx.x;
    const int wave = tid >> 6;
    const int lane = tid & 63;
    const int col  = lane & 15;
    const int kg   = lane >> 4;
    const int bid  = blockIdx.x;           // 0..863
    const int fp   = (bid & 1) * 2;        // fhi pair base
    const int p0   = (bid >> 1) * 256 + wave * 32;

    {
        const uint4* src = (const uint4*)(awp + (size_t)fp * 12288);
        uint4* dst = (uint4*)sA;
        #pragma unroll
        for (int i = 0; i < 6; i++)
            dst[i * 512 + tid] = src[i * 512 + tid];
    }

    bf16x8 bx[2][2], bh8[2][2];
    #pragma unroll
    for (int nt = 0; nt < 2; nt++) {
        const size_t pb = (size_t)(p0 + nt * 16 + col) * 64 + kg * 8;
        #pragma unroll
        for (int ks = 0; ks < 2; ks++) {
            bx[ks][nt]  = *(const bf16x8*)(x  + pb + ks * 32);
            bh8[ks][nt] = *(const bf16x8*)(hT + pb + ks * 32);
        }
    }

    __syncthreads();

    #pragma unroll
    for (int ff = 0; ff < 2; ff++) {
        const int fhi  = fp + ff;
        const int f0   = fhi * 16 + kg * 4;
        const int fcol = fhi * 16 + col;
        const unsigned short* ap = sA + ff * 12288 + lane * 8;

        const float4 b0v = *(const float4*)(bih + 0*F + f0);
        const float4 b2v = *(const float4*)(bih + 2*F + f0);
        const float4 b4v = *(const float4*)(bih + 4*F + f0);
        const float b0a[4] = {b0v.x, b0v.y, b0v.z, b0v.w};
        const float b2a[4] = {b2v.x, b2v.y, b2v.z, b2v.w};
        const float b4a[4] = {b4v.x, b4v.y, b4v.z, b4v.w};
        const float bih1f = bih[1*F + fcol];
        const float bih3f = bih[3*F + fcol];
        const float bih5f = bih[5*F + fcol];
        const float bhf   = bh[fcol];

        #pragma unroll
        for (int nt = 0; nt < 2; nt++) {
            const int p    = p0 + nt * 16 + col;
            const int prow = p0 + nt * 16 + kg * 4;

            // epilogue operands issued early (hide under MFMAs):
            const bf16x4 xv4 = *(const bf16x4*)(x + (size_t)p * 64 + f0);
            unsigned short hu[4];
            #pragma unroll
            for (int r = 0; r < 4; r++)
                hu[r] = hT[(size_t)(prow + r) * 64 + fcol];   // L2-hit scatter

            f32x4 acc_o[6], acc_h[6];
            #pragma unroll
            for (int j = 0; j < 6; j++) {
                acc_o[j] = (f32x4){0.f, 0.f, 0.f, 0.f};
                acc_h[j] = (f32x4){0.f, 0.f, 0.f, 0.f};
            }

            #pragma unroll
            for (int t = 0; t < 12; t++) {
                const int j = t >> 1;
                #pragma unroll
                for (int ks = 0; ks < 2; ks++) {
                    const bf16x8 a = *(const bf16x8*)(ap + (t * 2 + ks) * 512);
                    const bf16x8 dat = (t < 6) ? bx[ks][nt] : bh8[ks][nt];
                    if ((t & 1) == 0)
                        acc_o[j] = __builtin_amdgcn_mfma_f32_16x16x32_bf16(a, dat, acc_o[j], 0, 0, 0);
                    else
                        acc_h[j] = __builtin_amdgcn_mfma_f32_16x16x32_bf16(dat, a, acc_h[j], 0, 0, 0);
                }
            }

            float o[4];
            #pragma unroll
            for (int r = 0; r < 4; r++) {
                const float ri = sigmoidf_fast(acc_o[0][r] + b0a[r] + acc_o[3][r]);
                const float zi = sigmoidf_fast(acc_o[1][r] + b2a[r] + acc_o[4][r]);
                const float ch = tanhf_fast(ri * (acc_o[2][r] + b4a[r]) + acc_o[5][r]);
                const float xf = bf2f((unsigned short)xv4[r]);
                o[r] = fmaf(zi, ch - xf, xf);
            }
            *(uint2*)(out + (size_t)p * 64 + f0) =
                make_uint2(cvt_pk_bf16(o[0], o[1]), cvt_pk_bf16(o[2], o[3]));

            float hnr[4];
            #pragma unroll
            for (int r = 0; r < 4; r++) {
                const float rh = sigmoidf_fast(acc_h[0][r] + bih1f + acc_h[3][r]);
                const float zh = sigmoidf_fast(acc_h[1][r] + bih3f + acc_h[4][r]);
                const float ci = tanhf_fast(acc_h[2][r] + bih5f + rh * (acc_h[5][r] + bhf));
                const float hf = bf2f(hu[r]);
                hnr[r] = fmaf(zh, ci - hf, hf);
            }
            float4 hn;
            hn.x = hnr[0]; hn.y = hnr[1]; hn.z = hnr[2]; hn.w = hnr[3];
            *(float4*)(hnew + (size_t)fcol * SP + prow) = hn;
        }
    }
}

// ===========================================================================
extern "C" void kernel_launch(void* const* d_in, const int* in_sizes, int n_in,
                              void* d_out, int out_size, void* d_ws, size_t ws_size,
                              hipStream_t stream) {
    const float* x       = (const float*)d_in[0];
    const float* h1      = (const float*)d_in[1];
    const float* h2      = (const float*)d_in[2];
    const float* win_w1  = (const float*)d_in[3];
    const float* win_b1  = (const float*)d_in[4];
    const float* win_w2  = (const float*)d_in[5];
    const float* win_b2  = (const float*)d_in[6];
    const float* r1_wih  = (const float*)d_in[7];
    const float* r1_bih  = (const float*)d_in[8];
    const float* r1_whh  = (const float*)d_in[9];
    const float* r1_bh   = (const float*)d_in[10];
    const float* wbt_w1  = (const float*)d_in[11];
    const float* wbt_b1  = (const float*)d_in[12];
    const float* wbt_w2  = (const float*)d_in[13];
    const float* wbt_b2  = (const float*)d_in[14];
    const float* r2_wih  = (const float*)d_in[15];
    const float* r2_bih  = (const float*)d_in[16];
    const float* r2_whh  = (const float*)d_in[17];
    const float* r2_bh   = (const float*)d_in[18];
    const float* wout_w1 = (const float*)d_in[19];
    const float* wout_b1 = (const float*)d_in[20];
    const float* wout_w2 = (const float*)d_in[21];
    const float* wout_b2 = (const float*)d_in[22];

    float* eta_out = (float*)d_out;                       // 2*SP
    float* h1n_out = eta_out + 2 * SP;                    // 64*SP f32 [c][p]
    float* h2n_out = h1n_out + F * SP;

    // workspace: 3 bf16 [p][c] buffers + weight fragments
    unsigned short* bufA = (unsigned short*)d_ws;         // SP*64 u16
    unsigned short* bufB = bufA + (size_t)SP * 64;
    unsigned short* hT   = bufB + (size_t)SP * 64;
    unsigned short* lru1_awp = hT + (size_t)SP * 64;      // 49152
    unsigned short* lru2_awp = lru1_awp + 49152;          // 49152
    unsigned short* wbt1_f   = lru2_awp + 49152;          // 36864
    unsigned short* wout1_f  = wbt1_f + 36864;            // 36864
    unsigned short* win2_f   = wout1_f + 36864;           // 12288
    unsigned short* wbt2_f   = win2_f + 12288;            // 12288
    unsigned short* win1_awp = wbt2_f + 12288;            // 4096

    const dim3 blk(256);
    const dim3 blk512(512);

    // 1) prep: all repacks + transpose h1 -> hT
    prep_all<<<dim3(784 + 1728), blk, 0, stream>>>(
        r1_wih, r1_whh, r2_wih, r2_whh, wbt_w1, wout_w1, win_w2, wbt_w2,
        win_w1, h1,
        lru1_awp, lru2_awp, wbt1_f, wout1_f, win2_f, wbt2_f, win1_awp, hT);

    // 2) fused win stage: x -> bufB
    fused_win<<<dim3(576), blk512, 0, stream>>>(
        x, win1_awp, win_b1, win2_f, win_b2, bufB);

    // 3) LRU 1: bufB,hT -> bufA, h1n
    lru_mfma8<<<dim3(864), blk512, 0, stream>>>(
        bufB, hT, lru1_awp, r1_bih, r1_bh, bufA, h1n_out);

    // 4) fused wbt (bufA -> bufB) + transpose h2 -> hT rider
    fused_sp_tm_tr<<<dim3(576 + 1728), blk512, 0, stream>>>(
        bufA, wbt1_f, wbt_b1, wbt2_f, wbt_b2, bufB, h2, hT);

    // 5) LRU 2: bufB,hT -> bufA, h2n
    lru_mfma8<<<dim3(864), blk512, 0, stream>>>(
        bufB, hT, lru2_awp, r2_bih, r2_bh, bufA, h2n_out);

    // 6) fused wout: bufA -> eta
    fused_sp_tmout<<<dim3(576), blk512, 0, stream>>>(
        bufA, wout1_f, wout_b1, wout_w2, wout_b2, eta_out);
}

// Round 19
// 189.731 us; speedup vs baseline: 1.0339x; 1.0339x over previous
//
#include <hip/hip_runtime.h>

#define TT 12
#define DD 96
#define WW 96
#define PLANE (DD*WW)      // 9216
#define SP (TT*PLANE)      // 110592
#define F 64

typedef short bf16x8 __attribute__((ext_vector_type(8)));
typedef short bf16x4 __attribute__((ext_vector_type(4)));
typedef float f32x4  __attribute__((ext_vector_type(4)));

__device__ __forceinline__ float sigmoidf_fast(float x){
    return 1.0f / (1.0f + __expf(-x));
}
// tanh = 1 - 2/(e^{2x}+1): 5 ops, clamp-free (x->+inf -> 1; x->-inf -> -1)
__device__ __forceinline__ float tanhf_fast(float x){
    const float e = __expf(2.0f * x);
    return 1.0f - 2.0f / (e + 1.0f);
}
__device__ __forceinline__ unsigned short f2bf(float x){
    unsigned int u = __float_as_uint(x);
    u = (u + 0x7FFFu + ((u >> 16) & 1u)) >> 16;   // RNE
    return (unsigned short)u;
}
__device__ __forceinline__ float bf2f(unsigned short u){
    return __uint_as_float(((unsigned int)u) << 16);
}
__device__ __forceinline__ unsigned int cvt_pk_bf16(float lo, float hi){
    unsigned int r;
    asm("v_cvt_pk_bf16_f32 %0, %1, %2" : "=v"(r) : "v"(lo), "v"(hi));
    return r;
}

// ===========================================================================
// PREP: all weight repacks (200704 elems) + transpose h1 -> hT.
// blocks [0,784): repack flat; blocks [784, 784+1728): transpose tiles.
// ===========================================================================
__device__ __forceinline__ unsigned short repack_lru_elem(
    const float* wih, const float* whh, int idx)
{
    const int j    = idx & 7;
    const int lane = (idx >> 3) & 63;
    const int frag = idx >> 9;
    const int ks   = frag & 1;
    const int t    = (frag >> 1) % 12;
    const int fhi  = frag / 24;
    const int g    = (t < 6) ? t : t - 6;
    const int m    = g * 64 + fhi * 16 + (lane & 15);
    const int kk   = ks * 32 + (lane >> 4) * 8 + j;
    const float v  = (t < 6) ? wih[m * F + kk] : whh[m * F + kk];
    return f2bf(v);
}
__device__ __forceinline__ unsigned short repack_sp_elem(
    const float* wgt, int idx)
{
    const int j    = idx & 7;
    const int lane = (idx >> 3) & 63;
    const int frag = idx >> 9;
    const int fhi  = frag & 3;
    const int cl   = (frag >> 2) & 1;
    const int tap  = frag >> 3;
    const int f    = fhi * 16 + (lane & 15);
    const int c    = cl * 32 + (lane >> 4) * 8 + j;
    return f2bf(wgt[(f * 64 + c) * 9 + tap]);
}
__device__ __forceinline__ unsigned short repack_tm_elem(
    const float* wgt, int idx)
{
    const int j    = idx & 7;
    const int lane = (idx >> 3) & 63;
    const int frag = idx >> 9;
    const int fhi  = frag & 3;
    const int cl   = (frag >> 2) & 1;
    const int dt   = frag >> 3;
    const int f    = fhi * 16 + (lane & 15);
    const int c    = cl * 32 + (lane >> 4) * 8 + j;
    return f2bf(wgt[(f * 64 + c) * 3 + dt]);
}

__global__ __launch_bounds__(256) void prep_all(
    const float* __restrict__ r1_wih, const float* __restrict__ r1_whh,
    const float* __restrict__ r2_wih, const float* __restrict__ r2_whh,
    const float* __restrict__ wbt_w1, const float* __restrict__ wout_w1,
    const float* __restrict__ win_w2, const float* __restrict__ wbt_w2,
    const float* __restrict__ win_w1, const float* __restrict__ h1,
    unsigned short* __restrict__ lru1_awp, unsigned short* __restrict__ lru2_awp,
    unsigned short* __restrict__ wbt1_f, unsigned short* __restrict__ wout1_f,
    unsigned short* __restrict__ win2_f, unsigned short* __restrict__ wbt2_f,
    unsigned short* __restrict__ win1_awp, unsigned short* __restrict__ hT)
{
    __shared__ float tile[64 * 65];
    const int bx = blockIdx.x;
    if (bx < 784) {
        const int idx = bx * 256 + threadIdx.x;
        if (idx < 49152) {
            lru1_awp[idx] = repack_lru_elem(r1_wih, r1_whh, idx);
        } else if (idx < 98304) {
            const int i = idx - 49152;
            lru2_awp[i] = repack_lru_elem(r2_wih, r2_whh, i);
        } else if (idx < 135168) {
            const int i = idx - 98304;
            wbt1_f[i] = repack_sp_elem(wbt_w1, i);
        } else if (idx < 172032) {
            const int i = idx - 135168;
            wout1_f[i] = repack_sp_elem(wout_w1, i);
        } else if (idx < 184320) {
            const int i = idx - 172032;
            win2_f[i] = repack_tm_elem(win_w2, i);
        } else if (idx < 196608) {
            const int i = idx - 184320;
            wbt2_f[i] = repack_tm_elem(wbt_w2, i);
        } else if (idx < 200704) {
            // win1 im2col A-frags: frag = fhi*2+ks; k = c*16+tap (tap 9..15 pad 0)
            const int i    = idx - 196608;
            const int j    = i & 7;
            const int lane = (i >> 3) & 63;
            const int frag = i >> 9;          // 0..7
            const int ks   = frag & 1;
            const int fhi  = frag >> 1;
            const int m    = fhi * 16 + (lane & 15);
            const int kk   = ks * 32 + (lane >> 4) * 8 + j;
            const int c    = kk >> 4;
            const int tp   = kk & 15;
            win1_awp[i] = (tp < 9) ? f2bf(win_w1[(m * 4 + c) * 9 + tp])
                                   : (unsigned short)0;
        }
    } else {
        // transpose h1 tile (256 threads)
        const int tid  = threadIdx.x;
        const int wv   = tid >> 6;
        const int lane = tid & 63;
        const int p0   = (bx - 784) * 64;
        #pragma unroll
        for (int cc = 0; cc < 16; cc++) {
            const int c = cc * 4 + wv;
            tile[lane * 65 + c] = h1[(size_t)c * SP + p0 + lane];
        }
        __syncthreads();
        #pragma unroll
        for (int k = 0; k < 2; k++) {
            const int p  = (tid >> 3) + k * 32;
            const int c0 = (tid & 7) * 8;
            bf16x8 v;
            #pragma unroll
            for (int i = 0; i < 8; i++)
                v[i] = (short)f2bf(tile[p * 65 + c0 + i]);
            *(bf16x8*)(hT + (size_t)(p0 + p) * 64 + c0) = v;
        }
    }
}

// ===========================================================================
// FUSED win stage: im2col MFMA spatial conv (CIN=4, K=64 padded) -> LDS
// (swizzled bf16) -> temporal tm MFMA (weights LDS-staged) -> bufB.
// ===========================================================================
__global__ __launch_bounds__(512, 4) void fused_win(
    const float* __restrict__ x,
    const unsigned short* __restrict__ awp1, const float* __restrict__ bias1,
    const unsigned short* __restrict__ afr_tm, const float* __restrict__ bias_tm,
    unsigned short* __restrict__ out)
{
    __shared__ unsigned short y[8 * 2048];     // 32 KB
    __shared__ unsigned short wbuf[12288];     // 24 KB
    const int tid  = threadIdx.x;
    const int wv   = tid >> 6;
    const int lane = tid & 63;
    const int col  = lane & 15;
    const int kg   = lane >> 4;
    const int bx   = blockIdx.x;             // 0..575
    const int th   = bx / 288;
    const int rem  = bx - th * 288;
    const int d    = rem / 3;
    const int wseg = rem - d * 3;
    const int w0   = wseg * 32;
    const int t0   = th * 6;
    const int tsrc = (t0 + wv + 11) % 12;

    // stage tm weight table (24 KB) early -- used in phase B
    {
        const uint4* src = (const uint4*)afr_tm;
        uint4* dst = (uint4*)wbuf;
        #pragma unroll
        for (int i = 0; i < 3; i++)
            dst[i * 512 + tid] = src[i * 512 + tid];
    }

    // ---- phase A: spatial conv via im2col MFMA ----
    const int kgodd = kg & 1;
    const int c_lo  = kg >> 1;
    int wn[2];
    wn[0] = w0 + col;
    wn[1] = w0 + 16 + col;

    bf16x8 bf[2][2];
    const float* xb = x + (size_t)tsrc * PLANE;
    #pragma unroll
    for (int ks = 0; ks < 2; ks++) {
        const int c = ks * 2 + c_lo;
        const float* xc = xb + (size_t)c * SP;
        #pragma unroll
        for (int nt = 0; nt < 2; nt++) {
            bf16x8 v;
            #pragma unroll
            for (int j = 0; j < 8; j++) v[j] = 0;
            if (!kgodd) {
                #pragma unroll
                for (int j = 0; j < 8; j++) {   // tp = j = ddi*3+dwi
                    const int ddi = j / 3, dwi = j % 3;
                    const int dr = min(max(d + ddi - 1, 0), DD - 1);
                    const int wc = min(max(wn[nt] + dwi - 1, 0), WW - 1);
                    v[j] = (short)f2bf(xc[dr * WW + wc]);
                }
            } else {                             // tp = 8: ddi=2, dwi=2
                const int dr = min(d + 1, DD - 1);
                const int wc = min(wn[nt] + 1, WW - 1);
                v[0] = (short)f2bf(xc[dr * WW + wc]);
            }
            bf[ks][nt] = v;
        }
    }

    f32x4 acc[4][2];
    #pragma unroll
    for (int fhi = 0; fhi < 4; fhi++)
        #pragma unroll
        for (int nt = 0; nt < 2; nt++)
            acc[fhi][nt] = (f32x4){0.f, 0.f, 0.f, 0.f};

    #pragma unroll
    for (int ks = 0; ks < 2; ks++) {
        #pragma unroll
        for (int fhi = 0; fhi < 4; fhi++) {
            const bf16x8 a = *(const bf16x8*)(awp1 + (size_t)(fhi * 2 + ks) * 512 + lane * 8);
            acc[fhi][0] = __builtin_amdgcn_mfma_f32_16x16x32_bf16(a, bf[ks][0], acc[fhi][0], 0, 0, 0);
            acc[fhi][1] = __builtin_amdgcn_mfma_f32_16x16x32_bf16(a, bf[ks][1], acc[fhi][1], 0, 0, 0);
        }
    }

    // epilogue -> LDS (swizzled), bias + relu
    #pragma unroll
    for (int fhi = 0; fhi < 4; fhi++) {
        const float4 bv = *(const float4*)(bias1 + fhi * 16 + kg * 4);
        const int f0 = fhi * 16 + kg * 4;
        #pragma unroll
        for (int nt = 0; nt < 2; nt++) {
            const int pl = nt * 16 + col;
            const unsigned int lo = cvt_pk_bf16(fmaxf(acc[fhi][nt][0] + bv.x, 0.f),
                                                fmaxf(acc[fhi][nt][1] + bv.y, 0.f));
            const unsigned int hi = cvt_pk_bf16(fmaxf(acc[fhi][nt][2] + bv.z, 0.f),
                                                fmaxf(acc[fhi][nt][3] + bv.w, 0.f));
            const int idx = wv * 2048 + pl * 64 + (f0 ^ ((pl & 7) << 3));
            *(uint2*)(y + idx) = make_uint2(lo, hi);
        }
    }

    __syncthreads();

    // ---- phase B: temporal conv (waves 0..5), weights from wbuf ----
    if (wv < 6) {
        f32x4 acc2[4][2];
        #pragma unroll
        for (int fhi = 0; fhi < 4; fhi++)
            #pragma unroll
            for (int nt = 0; nt < 2; nt++)
                acc2[fhi][nt] = (f32x4){0.f, 0.f, 0.f, 0.f};

        const int cswz = (col & 7) << 3;
        const int lane8 = lane * 8;
        #pragma unroll
        for (int dt = 0; dt < 3; dt++) {
            const unsigned short* yb = y + (wv + dt) * 2048;
            #pragma unroll
            for (int cl = 0; cl < 2; cl++) {
                const int coff = (cl * 32 + kg * 8) ^ cswz;
                const bf16x8 b0 = *(const bf16x8*)(yb + col * 64 + coff);
                const bf16x8 b1 = *(const bf16x8*)(yb + (col + 16) * 64 + coff);
                const unsigned short* ap = wbuf + ((dt * 2 + cl) * 4) * 512 + lane8;
                #pragma unroll
                for (int fhi = 0; fhi < 4; fhi++) {
                    const bf16x8 a = *(const bf16x8*)(ap + fhi * 512);
                    acc2[fhi][0] = __builtin_amdgcn_mfma_f32_16x16x32_bf16(a, b0, acc2[fhi][0], 0, 0, 0);
                    acc2[fhi][1] = __builtin_amdgcn_mfma_f32_16x16x32_bf16(a, b1, acc2[fhi][1], 0, 0, 0);
                }
            }
        }

        const int pbase = (t0 + wv) * PLANE + d * WW + w0;
        #pragma unroll
        for (int fhi = 0; fhi < 4; fhi++) {
            const float4 bv = *(const float4*)(bias_tm + fhi * 16 + kg * 4);
            #pragma unroll
            for (int nt = 0; nt < 2; nt++) {
                const int p = pbase + nt * 16 + col;
                const unsigned int lo = cvt_pk_bf16(fmaxf(acc2[fhi][nt][0] + bv.x, 0.f),
                                                    fmaxf(acc2[fhi][nt][1] + bv.y, 0.f));
                const unsigned int hi = cvt_pk_bf16(fmaxf(acc2[fhi][nt][2] + bv.z, 0.f),
                                                    fmaxf(acc2[fhi][nt][3] + bv.w, 0.f));
                *(uint2*)(out + (size_t)p * 64 + fhi * 16 + kg * 4) = make_uint2(lo, hi);
            }
        }
    }
}

// ===========================================================================
// Shared phase A for the 64-channel spatial conv (wbt/wout), MFMA, -> LDS.
// Per-ddi-row LDS staging of the sp weight table (24 KB slices into wbuf).
// Must be called by ALL threads of the block (contains barriers).
// ===========================================================================
__device__ __forceinline__ void fused_phaseA_sp(
    const unsigned short* __restrict__ in,
    const unsigned short* __restrict__ afr_sp, const float* __restrict__ bias_sp,
    unsigned short* __restrict__ y, unsigned short* __restrict__ wbuf,
    int tid, int wv, int col, int kg, int d, int w0, int t)
{
    int wn[2];
    wn[0] = w0 + col;
    wn[1] = w0 + 16 + col;
    int voff[2][3];
    #pragma unroll
    for (int nt = 0; nt < 2; nt++)
        #pragma unroll
        for (int dwi = 0; dwi < 3; dwi++) {
            int wc = wn[nt] + dwi - 1;
            wc = min(max(wc, 0), WW - 1);
            voff[nt][dwi] = wc * 64 + kg * 8;
        }

    f32x4 acc[4][2];
    #pragma unroll
    for (int fhi = 0; fhi < 4; fhi++)
        #pragma unroll
        for (int nt = 0; nt < 2; nt++)
            acc[fhi][nt] = (f32x4){0.f, 0.f, 0.f, 0.f};

    const int tb = t * PLANE;
    const int lane8 = (kg * 16 + col) * 8;
    #pragma unroll
    for (int ddi = 0; ddi < 3; ddi++) {
        __syncthreads();   // previous row's wbuf reads complete
        {
            const uint4* src = (const uint4*)(afr_sp + (size_t)ddi * 12288);
            uint4* dst = (uint4*)wbuf;
            #pragma unroll
            for (int i = 0; i < 3; i++)
                dst[i * 512 + tid] = src[i * 512 + tid];
        }
        __syncthreads();

        int dr = d + ddi - 1;
        dr = min(max(dr, 0), DD - 1);
        const unsigned short* rp = in + (size_t)(tb + dr * WW) * 64;

        bf16x8 row[3][2][2];   // [dwi][cl][nt]
        #pragma unroll
        for (int dwi = 0; dwi < 3; dwi++)
            #pragma unroll
            for (int cl = 0; cl < 2; cl++) {
                row[dwi][cl][0] = *(const bf16x8*)(rp + voff[0][dwi] + cl * 32);
                row[dwi][cl][1] = *(const bf16x8*)(rp + voff[1][dwi] + cl * 32);
            }

        #pragma unroll
        for (int dwi = 0; dwi < 3; dwi++) {
            #pragma unroll
            for (int cl = 0; cl < 2; cl++) {
                const unsigned short* ap = wbuf + ((dwi * 2 + cl) * 4) * 512 + lane8;
                #pragma unroll
                for (int fhi = 0; fhi < 4; fhi++) {
                    const bf16x8 a = *(const bf16x8*)(ap + fhi * 512);
                    acc[fhi][0] = __builtin_amdgcn_mfma_f32_16x16x32_bf16(a, row[dwi][cl][0], acc[fhi][0], 0, 0, 0);
                    acc[fhi][1] = __builtin_amdgcn_mfma_f32_16x16x32_bf16(a, row[dwi][cl][1], acc[fhi][1], 0, 0, 0);
                }
            }
        }
    }

    #pragma unroll
    for (int fhi = 0; fhi < 4; fhi++) {
        const float4 bv = *(const float4*)(bias_sp + fhi * 16 + kg * 4);
        const int f0 = fhi * 16 + kg * 4;
        #pragma unroll
        for (int nt = 0; nt < 2; nt++) {
            const int pl = nt * 16 + col;
            const unsigned int lo = cvt_pk_bf16(fmaxf(acc[fhi][nt][0] + bv.x, 0.f),
                                                fmaxf(acc[fhi][nt][1] + bv.y, 0.f));
            const unsigned int hi = cvt_pk_bf16(fmaxf(acc[fhi][nt][2] + bv.z, 0.f),
                                                fmaxf(acc[fhi][nt][3] + bv.w, 0.f));
            const int idx = wv * 2048 + pl * 64 + (f0 ^ ((pl & 7) << 3));
            *(uint2*)(y + idx) = make_uint2(lo, hi);
        }
    }
}

// ===========================================================================
// FUSED wbt: spatial->LDS->temporal (blocks <576) + transpose h2 rider
// (blocks >=576, reuses hT which is dead after lru1).
// ===========================================================================
__global__ __launch_bounds__(512, 4) void fused_sp_tm_tr(
    const unsigned short* __restrict__ in,
    const unsigned short* __restrict__ afr_sp, const float* __restrict__ bias_sp,
    const unsigned short* __restrict__ afr_tm, const float* __restrict__ bias_tm,
    unsigned short* __restrict__ out,
    const float* __restrict__ h2, unsigned short* __restrict__ hT)
{
    __shared__ unsigned short y[8 * 2048];     // 32 KB (aliased by transpose)
    __shared__ unsigned short wbuf[12288];     // 24 KB weight staging
    const int tid  = threadIdx.x;
    const int wv   = tid >> 6;
    const int lane = tid & 63;
    const int bx   = blockIdx.x;

    if (bx >= 576) {
        // ---- transpose h2 tile: f32 [c][p] -> bf16 [p][c] ----
        float* tile = (float*)y;             // 64*65*4 = 16.6 KB < 32 KB
        const int p0 = (bx - 576) * 64;
        #pragma unroll
        for (int cc = 0; cc < 8; cc++) {
            const int c = cc * 8 + wv;
            tile[lane * 65 + c] = h2[(size_t)c * SP + p0 + lane];
        }
        __syncthreads();
        const int p  = tid >> 3;
        const int c0 = (tid & 7) * 8;
        bf16x8 v;
        #pragma unroll
        for (int i = 0; i < 8; i++)
            v[i] = (short)f2bf(tile[p * 65 + c0 + i]);
        *(bf16x8*)(hT + (size_t)(p0 + p) * 64 + c0) = v;
        return;
    }

    const int col  = lane & 15;
    const int kg   = lane >> 4;
    const int th   = bx / 288;
    const int rem  = bx - th * 288;
    const int d    = rem / 3;
    const int wseg = rem - d * 3;
    const int w0   = wseg * 32;
    const int t0   = th * 6;

    fused_phaseA_sp(in, afr_sp, bias_sp, y, wbuf, tid, wv, col, kg, d, w0,
                    (t0 + wv + 11) % 12);

    // restage wbuf with tm table; barrier also publishes y
    __syncthreads();
    {
        const uint4* src = (const uint4*)afr_tm;
        uint4* dst = (uint4*)wbuf;
        #pragma unroll
        for (int i = 0; i < 3; i++)
            dst[i * 512 + tid] = src[i * 512 + tid];
    }
    __syncthreads();

    if (wv < 6) {
        f32x4 acc[4][2];
        #pragma unroll
        for (int fhi = 0; fhi < 4; fhi++)
            #pragma unroll
            for (int nt = 0; nt < 2; nt++)
                acc[fhi][nt] = (f32x4){0.f, 0.f, 0.f, 0.f};

        const int cswz = (col & 7) << 3;
        const int lane8 = lane * 8;
        #pragma unroll
        for (int dt = 0; dt < 3; dt++) {
            const unsigned short* yb = y + (wv + dt) * 2048;
            #pragma unroll
            for (int cl = 0; cl < 2; cl++) {
                const int coff = (cl * 32 + kg * 8) ^ cswz;
                const bf16x8 b0 = *(const bf16x8*)(yb + col * 64 + coff);
                const bf16x8 b1 = *(const bf16x8*)(yb + (col + 16) * 64 + coff);
                const unsigned short* ap = wbuf + ((dt * 2 + cl) * 4) * 512 + lane8;
                #pragma unroll
                for (int fhi = 0; fhi < 4; fhi++) {
                    const bf16x8 a = *(const bf16x8*)(ap + fhi * 512);
                    acc[fhi][0] = __builtin_amdgcn_mfma_f32_16x16x32_bf16(a, b0, acc[fhi][0], 0, 0, 0);
                    acc[fhi][1] = __builtin_amdgcn_mfma_f32_16x16x32_bf16(a, b1, acc[fhi][1], 0, 0, 0);
                }
            }
        }

        const int pbase = (t0 + wv) * PLANE + d * WW + w0;
        #pragma unroll
        for (int fhi = 0; fhi < 4; fhi++) {
            const float4 bv = *(const float4*)(bias_tm + fhi * 16 + kg * 4);
            #pragma unroll
            for (int nt = 0; nt < 2; nt++) {
                const int p = pbase + nt * 16 + col;
                const unsigned int lo = cvt_pk_bf16(fmaxf(acc[fhi][nt][0] + bv.x, 0.f),
                                                    fmaxf(acc[fhi][nt][1] + bv.y, 0.f));
                const unsigned int hi = cvt_pk_bf16(fmaxf(acc[fhi][nt][2] + bv.z, 0.f),
                                                    fmaxf(acc[fhi][nt][3] + bv.w, 0.f));
                *(uint2*)(out + (size_t)p * 64 + fhi * 16 + kg * 4) = make_uint2(lo, hi);
            }
        }
    }
}

// ===========================================================================
// FUSED wout: spatial->LDS->final temporal (COUT=2, no relu, f32 out).
// ===========================================================================
__global__ __launch_bounds__(512, 4) void fused_sp_tmout(
    const unsigned short* __restrict__ in,
    const unsigned short* __restrict__ afr_sp, const float* __restrict__ bias_sp,
    const float* __restrict__ wgt, const float* __restrict__ bias_out,
    float* __restrict__ out)
{
    __shared__ unsigned short y[8 * 2048];     // 32 KB
    __shared__ unsigned short wbuf[12288];     // 24 KB weight staging
    const int tid  = threadIdx.x;
    const int wv   = tid >> 6;
    const int lane = tid & 63;
    const int col  = lane & 15;
    const int kg   = lane >> 4;
    const int bx   = blockIdx.x;
    const int th   = bx / 288;
    const int rem  = bx - th * 288;
    const int d    = rem / 3;
    const int wseg = rem - d * 3;
    const int w0   = wseg * 32;
    const int t0   = th * 6;

    fused_phaseA_sp(in, afr_sp, bias_sp, y, wbuf, tid, wv, col, kg, d, w0,
                    (t0 + wv + 11) % 12);
    __syncthreads();

    if (tid < 384) {
        const int pl = tid & 31;
        const int tv = (tid >> 5) % 6;
        const int ch = tid / 192;            // wave-uniform
        const int cswz = (pl & 7) << 3;
        float acc = 0.f;
        #pragma unroll
        for (int c0 = 0; c0 < 64; c0 += 8) {
            const int coff = pl * 64 + (c0 ^ cswz);
            const bf16x8 vm = *(const bf16x8*)(y + (tv    ) * 2048 + coff);
            const bf16x8 vc = *(const bf16x8*)(y + (tv + 1) * 2048 + coff);
            const bf16x8 vp = *(const bf16x8*)(y + (tv + 2) * 2048 + coff);
            #pragma unroll
            for (int jj = 0; jj < 8; jj++) {
                const int c = c0 + jj;
                const float* wq = wgt + (ch * 64 + c) * 3;
                acc += bf2f((unsigned short)vm[jj]) * wq[0]
                     + bf2f((unsigned short)vc[jj]) * wq[1]
                     + bf2f((unsigned short)vp[jj]) * wq[2];
            }
        }
        const int p = (t0 + tv) * PLANE + d * WW + w0 + pl;
        out[ch * SP + p] = acc + bias_out[ch];
    }
}

// ===========================================================================
// LRU via MFMA, v9: v7 memory pattern (LDS-staged weight pair, coalesced f32
// h float4 epilogue read) + cheap 5-op tanh and fma-form blends (v8's proven
// math half). 864 blocks x 512 threads.
// ===========================================================================
__global__ __launch_bounds__(512, 2) void lru_mfma9(
    const unsigned short* __restrict__ x, const unsigned short* __restrict__ hT,
    const float* __restrict__ h,
    const unsigned short* __restrict__ awp,
    const float* __restrict__ bih, const float* __restrict__ bh,
    unsigned short* __restrict__ out, float* __restrict__ hnew)
{
    __shared__ unsigned short sA[24576];   // 48 KB: awp slice for fhi pair
    const int tid  = threadIdx.x;
    const int wave = tid >> 6;
    const int lane = tid & 63;
    const int col  = lane & 15;
    const int kg   = lane >> 4;
    const int bid  = blockIdx.x;           // 0..863
    const int fp   = (bid & 1) * 2;        // fhi pair base
    const int p0   = (bid >> 1) * 256 + wave * 32;

    {
        const uint4* src = (const uint4*)(awp + (size_t)fp * 12288);
        uint4* dst = (uint4*)sA;
        #pragma unroll
        for (int i = 0; i < 6; i++)
            dst[i * 512 + tid] = src[i * 512 + tid];
    }

    bf16x8 bx[2][2], bh8[2][2];
    #pragma unroll
    for (int nt = 0; nt < 2; nt++) {
        const size_t pb = (size_t)(p0 + nt * 16 + col) * 64 + kg * 8;
        #pragma unroll
        for (int ks = 0; ks < 2; ks++) {
            bx[ks][nt]  = *(const bf16x8*)(x  + pb + ks * 32);
            bh8[ks][nt] = *(const bf16x8*)(hT + pb + ks * 32);
        }
    }

    __syncthreads();

    #pragma unroll
    for (int ff = 0; ff < 2; ff++) {
        const int fhi  = fp + ff;
        const int f0   = fhi * 16 + kg * 4;
        const int fcol = fhi * 16 + col;
        const unsigned short* ap = sA + ff * 12288 + lane * 8;

        const float4 b0v = *(const float4*)(bih + 0*F + f0);
        const float4 b2v = *(const float4*)(bih + 2*F + f0);
        const float4 b4v = *(const float4*)(bih + 4*F + f0);
        const float b0a[4] = {b0v.x, b0v.y, b0v.z, b0v.w};
        const float b2a[4] = {b2v.x, b2v.y, b2v.z, b2v.w};
        const float b4a[4] = {b4v.x, b4v.y, b4v.z, b4v.w};
        const float bih1f = bih[1*F + fcol];
        const float bih3f = bih[3*F + fcol];
        const float bih5f = bih[5*F + fcol];
        const float bhf   = bh[fcol];

        #pragma unroll
        for (int nt = 0; nt < 2; nt++) {
            const int p    = p0 + nt * 16 + col;
            const int prow = p0 + nt * 16 + kg * 4;

            // epilogue operands issued early (hide under MFMAs)
            const bf16x4 xv4 = *(const bf16x4*)(x + (size_t)p * 64 + f0);
            const float4 h4  = *(const float4*)(h + (size_t)fcol * SP + prow);

            f32x4 acc_o[6], acc_h[6];
            #pragma unroll
            for (int j = 0; j < 6; j++) {
                acc_o[j] = (f32x4){0.f, 0.f, 0.f, 0.f};
                acc_h[j] = (f32x4){0.f, 0.f, 0.f, 0.f};
            }

            #pragma unroll
            for (int t = 0; t < 12; t++) {
                const int j = t >> 1;
                #pragma unroll
                for (int ks = 0; ks < 2; ks++) {
                    const bf16x8 a = *(const bf16x8*)(ap + (t * 2 + ks) * 512);
                    const bf16x8 dat = (t < 6) ? bx[ks][nt] : bh8[ks][nt];
                    if ((t & 1) == 0)
                        acc_o[j] = __builtin_amdgcn_mfma_f32_16x16x32_bf16(a, dat, acc_o[j], 0, 0, 0);
                    else
                        acc_h[j] = __builtin_amdgcn_mfma_f32_16x16x32_bf16(dat, a, acc_h[j], 0, 0, 0);
                }
            }

            float o[4];
            #pragma unroll
            for (int r = 0; r < 4; r++) {
                const float ri = sigmoidf_fast(acc_o[0][r] + b0a[r] + acc_o[3][r]);
                const float zi = sigmoidf_fast(acc_o[1][r] + b2a[r] + acc_o[4][r]);
                const float ch = tanhf_fast(ri * (acc_o[2][r] + b4a[r]) + acc_o[5][r]);
                const float xf = bf2f((unsigned short)xv4[r]);
                o[r] = fmaf(zi, ch - xf, xf);
            }
            *(uint2*)(out + (size_t)p * 64 + f0) =
                make_uint2(cvt_pk_bf16(o[0], o[1]), cvt_pk_bf16(o[2], o[3]));

            float hnr[4];
            const float hsrc[4] = {h4.x, h4.y, h4.z, h4.w};
            #pragma unroll
            for (int r = 0; r < 4; r++) {
                const float rh = sigmoidf_fast(acc_h[0][r] + bih1f + acc_h[3][r]);
                const float zh = sigmoidf_fast(acc_h[1][r] + bih3f + acc_h[4][r]);
                const float ci = tanhf_fast(acc_h[2][r] + bih5f + rh * (acc_h[5][r] + bhf));
                hnr[r] = fmaf(zh, ci - hsrc[r], hsrc[r]);
            }
            float4 hn;
            hn.x = hnr[0]; hn.y = hnr[1]; hn.z = hnr[2]; hn.w = hnr[3];
            *(float4*)(hnew + (size_t)fcol * SP + prow) = hn;
        }
    }
}

// ===========================================================================
extern "C" void kernel_launch(void* const* d_in, const int* in_sizes, int n_in,
                              void* d_out, int out_size, void* d_ws, size_t ws_size,
                              hipStream_t stream) {
    const float* x       = (const float*)d_in[0];
    const float* h1      = (const float*)d_in[1];
    const float* h2      = (const float*)d_in[2];
    const float* win_w1  = (const float*)d_in[3];
    const float* win_b1  = (const float*)d_in[4];
    const float* win_w2  = (const float*)d_in[5];
    const float* win_b2  = (const float*)d_in[6];
    const float* r1_wih  = (const float*)d_in[7];
    const float* r1_bih  = (const float*)d_in[8];
    const float* r1_whh  = (const float*)d_in[9];
    const float* r1_bh   = (const float*)d_in[10];
    const float* wbt_w1  = (const float*)d_in[11];
    const float* wbt_b1  = (const float*)d_in[12];
    const float* wbt_w2  = (const float*)d_in[13];
    const float* wbt_b2  = (const float*)d_in[14];
    const float* r2_wih  = (const float*)d_in[15];
    const float* r2_bih  = (const float*)d_in[16];
    const float* r2_whh  = (const float*)d_in[17];
    const float* r2_bh   = (const float*)d_in[18];
    const float* wout_w1 = (const float*)d_in[19];
    const float* wout_b1 = (const float*)d_in[20];
    const float* wout_w2 = (const float*)d_in[21];
    const float* wout_b2 = (const float*)d_in[22];

    float* eta_out = (float*)d_out;                       // 2*SP
    float* h1n_out = eta_out + 2 * SP;                    // 64*SP f32 [c][p]
    float* h2n_out = h1n_out + F * SP;

    // workspace: 3 bf16 [p][c] buffers + weight fragments
    unsigned short* bufA = (unsigned short*)d_ws;         // SP*64 u16
    unsigned short* bufB = bufA + (size_t)SP * 64;
    unsigned short* hT   = bufB + (size_t)SP * 64;
    unsigned short* lru1_awp = hT + (size_t)SP * 64;      // 49152
    unsigned short* lru2_awp = lru1_awp + 49152;          // 49152
    unsigned short* wbt1_f   = lru2_awp + 49152;          // 36864
    unsigned short* wout1_f  = wbt1_f + 36864;            // 36864
    unsigned short* win2_f   = wout1_f + 36864;           // 12288
    unsigned short* wbt2_f   = win2_f + 12288;            // 12288
    unsigned short* win1_awp = wbt2_f + 12288;            // 4096

    const dim3 blk(256);
    const dim3 blk512(512);

    // 1) prep: all repacks + transpose h1 -> hT
    prep_all<<<dim3(784 + 1728), blk, 0, stream>>>(
        r1_wih, r1_whh, r2_wih, r2_whh, wbt_w1, wout_w1, win_w2, wbt_w2,
        win_w1, h1,
        lru1_awp, lru2_awp, wbt1_f, wout1_f, win2_f, wbt2_f, win1_awp, hT);

    // 2) fused win stage: x -> bufB
    fused_win<<<dim3(576), blk512, 0, stream>>>(
        x, win1_awp, win_b1, win2_f, win_b2, bufB);

    // 3) LRU 1: bufB,hT,h1 -> bufA, h1n
    lru_mfma9<<<dim3(864), blk512, 0, stream>>>(
        bufB, hT, h1, lru1_awp, r1_bih, r1_bh, bufA, h1n_out);

    // 4) fused wbt (bufA -> bufB) + transpose h2 -> hT rider
    fused_sp_tm_tr<<<dim3(576 + 1728), blk512, 0, stream>>>(
        bufA, wbt1_f, wbt_b1, wbt2_f, wbt_b2, bufB, h2, hT);

    // 5) LRU 2: bufB,hT,h2 -> bufA, h2n
    lru_mfma9<<<dim3(864), blk512, 0, stream>>>(
        bufB, hT, h2, lru2_awp, r2_bih, r2_bh, bufA, h2n_out);

    // 6) fused wout: bufA -> eta
    fused_sp_tmout<<<dim3(576), blk512, 0, stream>>>(
        bufA, wout1_f, wout_b1, wout_w2, wout_b2, eta_out);
}

// Round 20
// 183.508 us; speedup vs baseline: 1.0690x; 1.0339x over previous
//
#include <hip/hip_runtime.h>

#define TT 12
#define DD 96
#define WW 96
#define PLANE (DD*WW)      // 9216
#define SP (TT*PLANE)      // 110592
#define F 64

typedef short bf16x8 __attribute__((ext_vector_type(8)));
typedef short bf16x4 __attribute__((ext_vector_type(4)));
typedef float f32x4  __attribute__((ext_vector_type(4)));

__device__ __forceinline__ float sigmoidf_fast(float x){
    return 1.0f / (1.0f + __expf(-x));
}
// tanh = 1 - 2/(e^{2x}+1): 5 ops, clamp-free
__device__ __forceinline__ float tanhf_fast(float x){
    const float e = __expf(2.0f * x);
    return 1.0f - 2.0f / (e + 1.0f);
}
__device__ __forceinline__ unsigned short f2bf(float x){
    unsigned int u = __float_as_uint(x);
    u = (u + 0x7FFFu + ((u >> 16) & 1u)) >> 16;   // RNE
    return (unsigned short)u;
}
__device__ __forceinline__ float bf2f(unsigned short u){
    return __uint_as_float(((unsigned int)u) << 16);
}
__device__ __forceinline__ unsigned int cvt_pk_bf16(float lo, float hi){
    unsigned int r;
    asm("v_cvt_pk_bf16_f32 %0, %1, %2" : "=v"(r) : "v"(lo), "v"(hi));
    return r;
}

// ===========================================================================
// PREP: all weight repacks (200704 elems) + transpose h1 -> hT.
// blocks [0,784): repack flat; blocks [784, 784+1728): transpose tiles.
// ===========================================================================
__device__ __forceinline__ unsigned short repack_lru_elem(
    const float* wih, const float* whh, int idx)
{
    const int j    = idx & 7;
    const int lane = (idx >> 3) & 63;
    const int frag = idx >> 9;
    const int ks   = frag & 1;
    const int t    = (frag >> 1) % 12;
    const int fhi  = frag / 24;
    const int g    = (t < 6) ? t : t - 6;
    const int m    = g * 64 + fhi * 16 + (lane & 15);
    const int kk   = ks * 32 + (lane >> 4) * 8 + j;
    const float v  = (t < 6) ? wih[m * F + kk] : whh[m * F + kk];
    return f2bf(v);
}
__device__ __forceinline__ unsigned short repack_sp_elem(
    const float* wgt, int idx)
{
    const int j    = idx & 7;
    const int lane = (idx >> 3) & 63;
    const int frag = idx >> 9;
    const int fhi  = frag & 3;
    const int cl   = (frag >> 2) & 1;
    const int tap  = frag >> 3;
    const int f    = fhi * 16 + (lane & 15);
    const int c    = cl * 32 + (lane >> 4) * 8 + j;
    return f2bf(wgt[(f * 64 + c) * 9 + tap]);
}
__device__ __forceinline__ unsigned short repack_tm_elem(
    const float* wgt, int idx)
{
    const int j    = idx & 7;
    const int lane = (idx >> 3) & 63;
    const int frag = idx >> 9;
    const int fhi  = frag & 3;
    const int cl   = (frag >> 2) & 1;
    const int dt   = frag >> 3;
    const int f    = fhi * 16 + (lane & 15);
    const int c    = cl * 32 + (lane >> 4) * 8 + j;
    return f2bf(wgt[(f * 64 + c) * 3 + dt]);
}

__global__ __launch_bounds__(256) void prep_all(
    const float* __restrict__ r1_wih, const float* __restrict__ r1_whh,
    const float* __restrict__ r2_wih, const float* __restrict__ r2_whh,
    const float* __restrict__ wbt_w1, const float* __restrict__ wout_w1,
    const float* __restrict__ win_w2, const float* __restrict__ wbt_w2,
    const float* __restrict__ win_w1, const float* __restrict__ h1,
    unsigned short* __restrict__ lru1_awp, unsigned short* __restrict__ lru2_awp,
    unsigned short* __restrict__ wbt1_f, unsigned short* __restrict__ wout1_f,
    unsigned short* __restrict__ win2_f, unsigned short* __restrict__ wbt2_f,
    unsigned short* __restrict__ win1_awp, unsigned short* __restrict__ hT)
{
    __shared__ float tile[64 * 65];
    const int bx = blockIdx.x;
    if (bx < 784) {
        const int idx = bx * 256 + threadIdx.x;
        if (idx < 49152) {
            lru1_awp[idx] = repack_lru_elem(r1_wih, r1_whh, idx);
        } else if (idx < 98304) {
            const int i = idx - 49152;
            lru2_awp[i] = repack_lru_elem(r2_wih, r2_whh, i);
        } else if (idx < 135168) {
            const int i = idx - 98304;
            wbt1_f[i] = repack_sp_elem(wbt_w1, i);
        } else if (idx < 172032) {
            const int i = idx - 135168;
            wout1_f[i] = repack_sp_elem(wout_w1, i);
        } else if (idx < 184320) {
            const int i = idx - 172032;
            win2_f[i] = repack_tm_elem(win_w2, i);
        } else if (idx < 196608) {
            const int i = idx - 184320;
            wbt2_f[i] = repack_tm_elem(wbt_w2, i);
        } else if (idx < 200704) {
            // win1 im2col A-frags: frag = fhi*2+ks; k = c*16+tap (tap 9..15 pad 0)
            const int i    = idx - 196608;
            const int j    = i & 7;
            const int lane = (i >> 3) & 63;
            const int frag = i >> 9;          // 0..7
            const int ks   = frag & 1;
            const int fhi  = frag >> 1;
            const int m    = fhi * 16 + (lane & 15);
            const int kk   = ks * 32 + (lane >> 4) * 8 + j;
            const int c    = kk >> 4;
            const int tp   = kk & 15;
            win1_awp[i] = (tp < 9) ? f2bf(win_w1[(m * 4 + c) * 9 + tp])
                                   : (unsigned short)0;
        }
    } else {
        // transpose h1 tile (256 threads)
        const int tid  = threadIdx.x;
        const int wv   = tid >> 6;
        const int lane = tid & 63;
        const int p0   = (bx - 784) * 64;
        #pragma unroll
        for (int cc = 0; cc < 16; cc++) {
            const int c = cc * 4 + wv;
            tile[lane * 65 + c] = h1[(size_t)c * SP + p0 + lane];
        }
        __syncthreads();
        #pragma unroll
        for (int k = 0; k < 2; k++) {
            const int p  = (tid >> 3) + k * 32;
            const int c0 = (tid & 7) * 8;
            bf16x8 v;
            #pragma unroll
            for (int i = 0; i < 8; i++)
                v[i] = (short)f2bf(tile[p * 65 + c0 + i]);
            *(bf16x8*)(hT + (size_t)(p0 + p) * 64 + c0) = v;
        }
    }
}

// ===========================================================================
// FUSED win stage: im2col MFMA spatial conv (CIN=4, K=64 padded) -> LDS
// (swizzled bf16) -> temporal tm MFMA (weights LDS-staged) -> bufB.
// ===========================================================================
__global__ __launch_bounds__(512, 4) void fused_win(
    const float* __restrict__ x,
    const unsigned short* __restrict__ awp1, const float* __restrict__ bias1,
    const unsigned short* __restrict__ afr_tm, const float* __restrict__ bias_tm,
    unsigned short* __restrict__ out)
{
    __shared__ unsigned short y[8 * 2048];     // 32 KB
    __shared__ unsigned short wbuf[12288];     // 24 KB
    const int tid  = threadIdx.x;
    const int wv   = tid >> 6;
    const int lane = tid & 63;
    const int col  = lane & 15;
    const int kg   = lane >> 4;
    const int bx   = blockIdx.x;             // 0..575
    const int th   = bx / 288;
    const int rem  = bx - th * 288;
    const int d    = rem / 3;
    const int wseg = rem - d * 3;
    const int w0   = wseg * 32;
    const int t0   = th * 6;
    const int tsrc = (t0 + wv + 11) % 12;

    // stage tm weight table (24 KB) early -- used in phase B
    {
        const uint4* src = (const uint4*)afr_tm;
        uint4* dst = (uint4*)wbuf;
        #pragma unroll
        for (int i = 0; i < 3; i++)
            dst[i * 512 + tid] = src[i * 512 + tid];
    }

    // ---- phase A: spatial conv via im2col MFMA ----
    const int kgodd = kg & 1;
    const int c_lo  = kg >> 1;
    int wn[2];
    wn[0] = w0 + col;
    wn[1] = w0 + 16 + col;

    bf16x8 bf[2][2];
    const float* xb = x + (size_t)tsrc * PLANE;
    #pragma unroll
    for (int ks = 0; ks < 2; ks++) {
        const int c = ks * 2 + c_lo;
        const float* xc = xb + (size_t)c * SP;
        #pragma unroll
        for (int nt = 0; nt < 2; nt++) {
            bf16x8 v;
            #pragma unroll
            for (int j = 0; j < 8; j++) v[j] = 0;
            if (!kgodd) {
                #pragma unroll
                for (int j = 0; j < 8; j++) {   // tp = j = ddi*3+dwi
                    const int ddi = j / 3, dwi = j % 3;
                    const int dr = min(max(d + ddi - 1, 0), DD - 1);
                    const int wc = min(max(wn[nt] + dwi - 1, 0), WW - 1);
                    v[j] = (short)f2bf(xc[dr * WW + wc]);
                }
            } else {                             // tp = 8: ddi=2, dwi=2
                const int dr = min(d + 1, DD - 1);
                const int wc = min(wn[nt] + 1, WW - 1);
                v[0] = (short)f2bf(xc[dr * WW + wc]);
            }
            bf[ks][nt] = v;
        }
    }

    f32x4 acc[4][2];
    #pragma unroll
    for (int fhi = 0; fhi < 4; fhi++)
        #pragma unroll
        for (int nt = 0; nt < 2; nt++)
            acc[fhi][nt] = (f32x4){0.f, 0.f, 0.f, 0.f};

    #pragma unroll
    for (int ks = 0; ks < 2; ks++) {
        #pragma unroll
        for (int fhi = 0; fhi < 4; fhi++) {
            const bf16x8 a = *(const bf16x8*)(awp1 + (size_t)(fhi * 2 + ks) * 512 + lane * 8);
            acc[fhi][0] = __builtin_amdgcn_mfma_f32_16x16x32_bf16(a, bf[ks][0], acc[fhi][0], 0, 0, 0);
            acc[fhi][1] = __builtin_amdgcn_mfma_f32_16x16x32_bf16(a, bf[ks][1], acc[fhi][1], 0, 0, 0);
        }
    }

    // epilogue -> LDS (swizzled), bias + relu
    #pragma unroll
    for (int fhi = 0; fhi < 4; fhi++) {
        const float4 bv = *(const float4*)(bias1 + fhi * 16 + kg * 4);
        const int f0 = fhi * 16 + kg * 4;
        #pragma unroll
        for (int nt = 0; nt < 2; nt++) {
            const int pl = nt * 16 + col;
            const unsigned int lo = cvt_pk_bf16(fmaxf(acc[fhi][nt][0] + bv.x, 0.f),
                                                fmaxf(acc[fhi][nt][1] + bv.y, 0.f));
            const unsigned int hi = cvt_pk_bf16(fmaxf(acc[fhi][nt][2] + bv.z, 0.f),
                                                fmaxf(acc[fhi][nt][3] + bv.w, 0.f));
            const int idx = wv * 2048 + pl * 64 + (f0 ^ ((pl & 7) << 3));
            *(uint2*)(y + idx) = make_uint2(lo, hi);
        }
    }

    __syncthreads();

    // ---- phase B: temporal conv (waves 0..5), weights from wbuf ----
    if (wv < 6) {
        f32x4 acc2[4][2];
        #pragma unroll
        for (int fhi = 0; fhi < 4; fhi++)
            #pragma unroll
            for (int nt = 0; nt < 2; nt++)
                acc2[fhi][nt] = (f32x4){0.f, 0.f, 0.f, 0.f};

        const int cswz = (col & 7) << 3;
        const int lane8 = lane * 8;
        #pragma unroll
        for (int dt = 0; dt < 3; dt++) {
            const unsigned short* yb = y + (wv + dt) * 2048;
            #pragma unroll
            for (int cl = 0; cl < 2; cl++) {
                const int coff = (cl * 32 + kg * 8) ^ cswz;
                const bf16x8 b0 = *(const bf16x8*)(yb + col * 64 + coff);
                const bf16x8 b1 = *(const bf16x8*)(yb + (col + 16) * 64 + coff);
                const unsigned short* ap = wbuf + ((dt * 2 + cl) * 4) * 512 + lane8;
                #pragma unroll
                for (int fhi = 0; fhi < 4; fhi++) {
                    const bf16x8 a = *(const bf16x8*)(ap + fhi * 512);
                    acc2[fhi][0] = __builtin_amdgcn_mfma_f32_16x16x32_bf16(a, b0, acc2[fhi][0], 0, 0, 0);
                    acc2[fhi][1] = __builtin_amdgcn_mfma_f32_16x16x32_bf16(a, b1, acc2[fhi][1], 0, 0, 0);
                }
            }
        }

        const int pbase = (t0 + wv) * PLANE + d * WW + w0;
        #pragma unroll
        for (int fhi = 0; fhi < 4; fhi++) {
            const float4 bv = *(const float4*)(bias_tm + fhi * 16 + kg * 4);
            #pragma unroll
            for (int nt = 0; nt < 2; nt++) {
                const int p = pbase + nt * 16 + col;
                const unsigned int lo = cvt_pk_bf16(fmaxf(acc2[fhi][nt][0] + bv.x, 0.f),
                                                    fmaxf(acc2[fhi][nt][1] + bv.y, 0.f));
                const unsigned int hi = cvt_pk_bf16(fmaxf(acc2[fhi][nt][2] + bv.z, 0.f),
                                                    fmaxf(acc2[fhi][nt][3] + bv.w, 0.f));
                *(uint2*)(out + (size_t)p * 64 + fhi * 16 + kg * 4) = make_uint2(lo, hi);
            }
        }
    }
}

// ===========================================================================
// Shared phase A for the 64-channel spatial conv (wbt/wout), MFMA, -> LDS.
// Per-ddi-row LDS staging of the sp weight table (24 KB slices into wbuf).
// Must be called by ALL threads of the block (contains barriers).
// ===========================================================================
__device__ __forceinline__ void fused_phaseA_sp(
    const unsigned short* __restrict__ in,
    const unsigned short* __restrict__ afr_sp, const float* __restrict__ bias_sp,
    unsigned short* __restrict__ y, unsigned short* __restrict__ wbuf,
    int tid, int wv, int col, int kg, int d, int w0, int t)
{
    int wn[2];
    wn[0] = w0 + col;
    wn[1] = w0 + 16 + col;
    int voff[2][3];
    #pragma unroll
    for (int nt = 0; nt < 2; nt++)
        #pragma unroll
        for (int dwi = 0; dwi < 3; dwi++) {
            int wc = wn[nt] + dwi - 1;
            wc = min(max(wc, 0), WW - 1);
            voff[nt][dwi] = wc * 64 + kg * 8;
        }

    f32x4 acc[4][2];
    #pragma unroll
    for (int fhi = 0; fhi < 4; fhi++)
        #pragma unroll
        for (int nt = 0; nt < 2; nt++)
            acc[fhi][nt] = (f32x4){0.f, 0.f, 0.f, 0.f};

    const int tb = t * PLANE;
    const int lane8 = (kg * 16 + col) * 8;
    #pragma unroll
    for (int ddi = 0; ddi < 3; ddi++) {
        __syncthreads();   // previous row's wbuf reads complete
        {
            const uint4* src = (const uint4*)(afr_sp + (size_t)ddi * 12288);
            uint4* dst = (uint4*)wbuf;
            #pragma unroll
            for (int i = 0; i < 3; i++)
                dst[i * 512 + tid] = src[i * 512 + tid];
        }
        __syncthreads();

        int dr = d + ddi - 1;
        dr = min(max(dr, 0), DD - 1);
        const unsigned short* rp = in + (size_t)(tb + dr * WW) * 64;

        bf16x8 row[3][2][2];   // [dwi][cl][nt]
        #pragma unroll
        for (int dwi = 0; dwi < 3; dwi++)
            #pragma unroll
            for (int cl = 0; cl < 2; cl++) {
                row[dwi][cl][0] = *(const bf16x8*)(rp + voff[0][dwi] + cl * 32);
                row[dwi][cl][1] = *(const bf16x8*)(rp + voff[1][dwi] + cl * 32);
            }

        #pragma unroll
        for (int dwi = 0; dwi < 3; dwi++) {
            #pragma unroll
            for (int cl = 0; cl < 2; cl++) {
                const unsigned short* ap = wbuf + ((dwi * 2 + cl) * 4) * 512 + lane8;
                #pragma unroll
                for (int fhi = 0; fhi < 4; fhi++) {
                    const bf16x8 a = *(const bf16x8*)(ap + fhi * 512);
                    acc[fhi][0] = __builtin_amdgcn_mfma_f32_16x16x32_bf16(a, row[dwi][cl][0], acc[fhi][0], 0, 0, 0);
                    acc[fhi][1] = __builtin_amdgcn_mfma_f32_16x16x32_bf16(a, row[dwi][cl][1], acc[fhi][1], 0, 0, 0);
                }
            }
        }
    }

    #pragma unroll
    for (int fhi = 0; fhi < 4; fhi++) {
        const float4 bv = *(const float4*)(bias_sp + fhi * 16 + kg * 4);
        const int f0 = fhi * 16 + kg * 4;
        #pragma unroll
        for (int nt = 0; nt < 2; nt++) {
            const int pl = nt * 16 + col;
            const unsigned int lo = cvt_pk_bf16(fmaxf(acc[fhi][nt][0] + bv.x, 0.f),
                                                fmaxf(acc[fhi][nt][1] + bv.y, 0.f));
            const unsigned int hi = cvt_pk_bf16(fmaxf(acc[fhi][nt][2] + bv.z, 0.f),
                                                fmaxf(acc[fhi][nt][3] + bv.w, 0.f));
            const int idx = wv * 2048 + pl * 64 + (f0 ^ ((pl & 7) << 3));
            *(uint2*)(y + idx) = make_uint2(lo, hi);
        }
    }
}

// ===========================================================================
// FUSED wbt: spatial->LDS->temporal (blocks <576) + transpose h2 rider
// (blocks >=576, reuses hT which is dead after lru1).
// ===========================================================================
__global__ __launch_bounds__(512, 4) void fused_sp_tm_tr(
    const unsigned short* __restrict__ in,
    const unsigned short* __restrict__ afr_sp, const float* __restrict__ bias_sp,
    const unsigned short* __restrict__ afr_tm, const float* __restrict__ bias_tm,
    unsigned short* __restrict__ out,
    const float* __restrict__ h2, unsigned short* __restrict__ hT)
{
    __shared__ unsigned short y[8 * 2048];     // 32 KB (aliased by transpose)
    __shared__ unsigned short wbuf[12288];     // 24 KB weight staging
    const int tid  = threadIdx.x;
    const int wv   = tid >> 6;
    const int lane = tid & 63;
    const int bx   = blockIdx.x;

    if (bx >= 576) {
        // ---- transpose h2 tile: f32 [c][p] -> bf16 [p][c] ----
        float* tile = (float*)y;             // 64*65*4 = 16.6 KB < 32 KB
        const int p0 = (bx - 576) * 64;
        #pragma unroll
        for (int cc = 0; cc < 8; cc++) {
            const int c = cc * 8 + wv;
            tile[lane * 65 + c] = h2[(size_t)c * SP + p0 + lane];
        }
        __syncthreads();
        const int p  = tid >> 3;
        const int c0 = (tid & 7) * 8;
        bf16x8 v;
        #pragma unroll
        for (int i = 0; i < 8; i++)
            v[i] = (short)f2bf(tile[p * 65 + c0 + i]);
        *(bf16x8*)(hT + (size_t)(p0 + p) * 64 + c0) = v;
        return;
    }

    const int col  = lane & 15;
    const int kg   = lane >> 4;
    const int th   = bx / 288;
    const int rem  = bx - th * 288;
    const int d    = rem / 3;
    const int wseg = rem - d * 3;
    const int w0   = wseg * 32;
    const int t0   = th * 6;

    fused_phaseA_sp(in, afr_sp, bias_sp, y, wbuf, tid, wv, col, kg, d, w0,
                    (t0 + wv + 11) % 12);

    // restage wbuf with tm table; barrier also publishes y
    __syncthreads();
    {
        const uint4* src = (const uint4*)afr_tm;
        uint4* dst = (uint4*)wbuf;
        #pragma unroll
        for (int i = 0; i < 3; i++)
            dst[i * 512 + tid] = src[i * 512 + tid];
    }
    __syncthreads();

    if (wv < 6) {
        f32x4 acc[4][2];
        #pragma unroll
        for (int fhi = 0; fhi < 4; fhi++)
            #pragma unroll
            for (int nt = 0; nt < 2; nt++)
                acc[fhi][nt] = (f32x4){0.f, 0.f, 0.f, 0.f};

        const int cswz = (col & 7) << 3;
        const int lane8 = lane * 8;
        #pragma unroll
        for (int dt = 0; dt < 3; dt++) {
            const unsigned short* yb = y + (wv + dt) * 2048;
            #pragma unroll
            for (int cl = 0; cl < 2; cl++) {
                const int coff = (cl * 32 + kg * 8) ^ cswz;
                const bf16x8 b0 = *(const bf16x8*)(yb + col * 64 + coff);
                const bf16x8 b1 = *(const bf16x8*)(yb + (col + 16) * 64 + coff);
                const unsigned short* ap = wbuf + ((dt * 2 + cl) * 4) * 512 + lane8;
                #pragma unroll
                for (int fhi = 0; fhi < 4; fhi++) {
                    const bf16x8 a = *(const bf16x8*)(ap + fhi * 512);
                    acc[fhi][0] = __builtin_amdgcn_mfma_f32_16x16x32_bf16(a, b0, acc[fhi][0], 0, 0, 0);
                    acc[fhi][1] = __builtin_amdgcn_mfma_f32_16x16x32_bf16(a, b1, acc[fhi][1], 0, 0, 0);
                }
            }
        }

        const int pbase = (t0 + wv) * PLANE + d * WW + w0;
        #pragma unroll
        for (int fhi = 0; fhi < 4; fhi++) {
            const float4 bv = *(const float4*)(bias_tm + fhi * 16 + kg * 4);
            #pragma unroll
            for (int nt = 0; nt < 2; nt++) {
                const int p = pbase + nt * 16 + col;
                const unsigned int lo = cvt_pk_bf16(fmaxf(acc[fhi][nt][0] + bv.x, 0.f),
                                                    fmaxf(acc[fhi][nt][1] + bv.y, 0.f));
                const unsigned int hi = cvt_pk_bf16(fmaxf(acc[fhi][nt][2] + bv.z, 0.f),
                                                    fmaxf(acc[fhi][nt][3] + bv.w, 0.f));
                *(uint2*)(out + (size_t)p * 64 + fhi * 16 + kg * 4) = make_uint2(lo, hi);
            }
        }
    }
}

// ===========================================================================
// FUSED wout: spatial->LDS->final temporal (COUT=2, no relu, f32 out).
// ===========================================================================
__global__ __launch_bounds__(512, 4) void fused_sp_tmout(
    const unsigned short* __restrict__ in,
    const unsigned short* __restrict__ afr_sp, const float* __restrict__ bias_sp,
    const float* __restrict__ wgt, const float* __restrict__ bias_out,
    float* __restrict__ out)
{
    __shared__ unsigned short y[8 * 2048];     // 32 KB
    __shared__ unsigned short wbuf[12288];     // 24 KB weight staging
    const int tid  = threadIdx.x;
    const int wv   = tid >> 6;
    const int lane = tid & 63;
    const int col  = lane & 15;
    const int kg   = lane >> 4;
    const int bx   = blockIdx.x;
    const int th   = bx / 288;
    const int rem  = bx - th * 288;
    const int d    = rem / 3;
    const int wseg = rem - d * 3;
    const int w0   = wseg * 32;
    const int t0   = th * 6;

    fused_phaseA_sp(in, afr_sp, bias_sp, y, wbuf, tid, wv, col, kg, d, w0,
                    (t0 + wv + 11) % 12);
    __syncthreads();

    if (tid < 384) {
        const int pl = tid & 31;
        const int tv = (tid >> 5) % 6;
        const int ch = tid / 192;            // wave-uniform
        const int cswz = (pl & 7) << 3;
        float acc = 0.f;
        #pragma unroll
        for (int c0 = 0; c0 < 64; c0 += 8) {
            const int coff = pl * 64 + (c0 ^ cswz);
            const bf16x8 vm = *(const bf16x8*)(y + (tv    ) * 2048 + coff);
            const bf16x8 vc = *(const bf16x8*)(y + (tv + 1) * 2048 + coff);
            const bf16x8 vp = *(const bf16x8*)(y + (tv + 2) * 2048 + coff);
            #pragma unroll
            for (int jj = 0; jj < 8; jj++) {
                const int c = c0 + jj;
                const float* wq = wgt + (ch * 64 + c) * 3;
                acc += bf2f((unsigned short)vm[jj]) * wq[0]
                     + bf2f((unsigned short)vc[jj]) * wq[1]
                     + bf2f((unsigned short)vp[jj]) * wq[2];
            }
        }
        const int p = (t0 + tv) * PLANE + d * WW + w0 + pl;
        out[ch * SP + p] = acc + bias_out[ch];
    }
}

// ===========================================================================
// LRU via MFMA, v10: nt-INNER MFMA loop. Each A-fragment is ds_read ONCE and
// consumed by both nt-columns (halves LDS-pipe traffic 96->48 reads/wave);
// both nt accumulator sets live (24 f32x4) + data frags held in regs.
// Block = 4 waves x 32 pos = 128 positions, one fhi pair; grid 1728.
// launch_bounds(256,1): ~180 VGPR + 48 KB LDS -> 3 waves/SIMD.
// ===========================================================================
__global__ __launch_bounds__(256, 1) void lru_mfma10(
    const unsigned short* __restrict__ x, const unsigned short* __restrict__ hT,
    const float* __restrict__ h,
    const unsigned short* __restrict__ awp,
    const float* __restrict__ bih, const float* __restrict__ bh,
    unsigned short* __restrict__ out, float* __restrict__ hnew)
{
    __shared__ unsigned short sA[24576];   // 48 KB: awp slice for fhi pair
    const int tid  = threadIdx.x;
    const int wave = tid >> 6;
    const int lane = tid & 63;
    const int col  = lane & 15;
    const int kg   = lane >> 4;
    const int bid  = blockIdx.x;           // 0..1727
    const int fp   = (bid & 1) * 2;        // fhi pair base
    const int p0   = (bid >> 1) * 128 + wave * 32;

    {
        const uint4* src = (const uint4*)(awp + (size_t)fp * 12288);
        uint4* dst = (uint4*)sA;
        #pragma unroll
        for (int i = 0; i < 12; i++)
            dst[i * 256 + tid] = src[i * 256 + tid];
    }

    bf16x8 bx[2][2], bh8[2][2];
    #pragma unroll
    for (int nt = 0; nt < 2; nt++) {
        const size_t pb = (size_t)(p0 + nt * 16 + col) * 64 + kg * 8;
        #pragma unroll
        for (int ks = 0; ks < 2; ks++) {
            bx[ks][nt]  = *(const bf16x8*)(x  + pb + ks * 32);
            bh8[ks][nt] = *(const bf16x8*)(hT + pb + ks * 32);
        }
    }

    __syncthreads();

    #pragma unroll
    for (int ff = 0; ff < 2; ff++) {
        const int fhi  = fp + ff;
        const int f0   = fhi * 16 + kg * 4;
        const int fcol = fhi * 16 + col;
        const unsigned short* ap = sA + ff * 12288 + lane * 8;

        const float4 b0v = *(const float4*)(bih + 0*F + f0);
        const float4 b2v = *(const float4*)(bih + 2*F + f0);
        const float4 b4v = *(const float4*)(bih + 4*F + f0);
        const float b0a[4] = {b0v.x, b0v.y, b0v.z, b0v.w};
        const float b2a[4] = {b2v.x, b2v.y, b2v.z, b2v.w};
        const float b4a[4] = {b4v.x, b4v.y, b4v.z, b4v.w};
        const float bih1f = bih[1*F + fcol];
        const float bih3f = bih[3*F + fcol];
        const float bih5f = bih[5*F + fcol];
        const float bhf   = bh[fcol];

        // epilogue operands issued early (hide under MFMAs)
        bf16x4 xv4[2];
        float4 h4[2];
        #pragma unroll
        for (int nt = 0; nt < 2; nt++) {
            const int p    = p0 + nt * 16 + col;
            const int prow = p0 + nt * 16 + kg * 4;
            xv4[nt] = *(const bf16x4*)(x + (size_t)p * 64 + f0);
            h4[nt]  = *(const float4*)(h + (size_t)fcol * SP + prow);
        }

        // both nt accumulator sets live; each frag ds_read ONCE, used twice
        f32x4 aco0[6], aco1[6], ach0[6], ach1[6];
        #pragma unroll
        for (int j = 0; j < 6; j++) {
            aco0[j] = (f32x4){0.f, 0.f, 0.f, 0.f};
            aco1[j] = (f32x4){0.f, 0.f, 0.f, 0.f};
            ach0[j] = (f32x4){0.f, 0.f, 0.f, 0.f};
            ach1[j] = (f32x4){0.f, 0.f, 0.f, 0.f};
        }

        #pragma unroll
        for (int t = 0; t < 12; t++) {
            const int j = t >> 1;
            #pragma unroll
            for (int ks = 0; ks < 2; ks++) {
                const bf16x8 a = *(const bf16x8*)(ap + (t * 2 + ks) * 512);
                const bf16x8 d0 = (t < 6) ? bx[ks][0] : bh8[ks][0];
                const bf16x8 d1 = (t < 6) ? bx[ks][1] : bh8[ks][1];
                if ((t & 1) == 0) {
                    aco0[j] = __builtin_amdgcn_mfma_f32_16x16x32_bf16(a, d0, aco0[j], 0, 0, 0);
                    aco1[j] = __builtin_amdgcn_mfma_f32_16x16x32_bf16(a, d1, aco1[j], 0, 0, 0);
                } else {
                    ach0[j] = __builtin_amdgcn_mfma_f32_16x16x32_bf16(d0, a, ach0[j], 0, 0, 0);
                    ach1[j] = __builtin_amdgcn_mfma_f32_16x16x32_bf16(d1, a, ach1[j], 0, 0, 0);
                }
            }
        }

        #pragma unroll
        for (int nt = 0; nt < 2; nt++) {
            const int p    = p0 + nt * 16 + col;
            const int prow = p0 + nt * 16 + kg * 4;
            const f32x4* aco = nt ? aco1 : aco0;
            const f32x4* ach = nt ? ach1 : ach0;

            float o[4];
            #pragma unroll
            for (int r = 0; r < 4; r++) {
                const float ri = sigmoidf_fast(aco[0][r] + b0a[r] + aco[3][r]);
                const float zi = sigmoidf_fast(aco[1][r] + b2a[r] + aco[4][r]);
                const float ch = tanhf_fast(ri * (aco[2][r] + b4a[r]) + aco[5][r]);
                const float xf = bf2f((unsigned short)xv4[nt][r]);
                o[r] = fmaf(zi, ch - xf, xf);
            }
            *(uint2*)(out + (size_t)p * 64 + f0) =
                make_uint2(cvt_pk_bf16(o[0], o[1]), cvt_pk_bf16(o[2], o[3]));

            const float hsrc[4] = {h4[nt].x, h4[nt].y, h4[nt].z, h4[nt].w};
            float hnr[4];
            #pragma unroll
            for (int r = 0; r < 4; r++) {
                const float rh = sigmoidf_fast(ach[0][r] + bih1f + ach[3][r]);
                const float zh = sigmoidf_fast(ach[1][r] + bih3f + ach[4][r]);
                const float ci = tanhf_fast(ach[2][r] + bih5f + rh * (ach[5][r] + bhf));
                hnr[r] = fmaf(zh, ci - hsrc[r], hsrc[r]);
            }
            float4 hn;
            hn.x = hnr[0]; hn.y = hnr[1]; hn.z = hnr[2]; hn.w = hnr[3];
            *(float4*)(hnew + (size_t)fcol * SP + prow) = hn;
        }
    }
}

// ===========================================================================
extern "C" void kernel_launch(void* const* d_in, const int* in_sizes, int n_in,
                              void* d_out, int out_size, void* d_ws, size_t ws_size,
                              hipStream_t stream) {
    const float* x       = (const float*)d_in[0];
    const float* h1      = (const float*)d_in[1];
    const float* h2      = (const float*)d_in[2];
    const float* win_w1  = (const float*)d_in[3];
    const float* win_b1  = (const float*)d_in[4];
    const float* win_w2  = (const float*)d_in[5];
    const float* win_b2  = (const float*)d_in[6];
    const float* r1_wih  = (const float*)d_in[7];
    const float* r1_bih  = (const float*)d_in[8];
    const float* r1_whh  = (const float*)d_in[9];
    const float* r1_bh   = (const float*)d_in[10];
    const float* wbt_w1  = (const float*)d_in[11];
    const float* wbt_b1  = (const float*)d_in[12];
    const float* wbt_w2  = (const float*)d_in[13];
    const float* wbt_b2  = (const float*)d_in[14];
    const float* r2_wih  = (const float*)d_in[15];
    const float* r2_bih  = (const float*)d_in[16];
    const float* r2_whh  = (const float*)d_in[17];
    const float* r2_bh   = (const float*)d_in[18];
    const float* wout_w1 = (const float*)d_in[19];
    const float* wout_b1 = (const float*)d_in[20];
    const float* wout_w2 = (const float*)d_in[21];
    const float* wout_b2 = (const float*)d_in[22];

    float* eta_out = (float*)d_out;                       // 2*SP
    float* h1n_out = eta_out + 2 * SP;                    // 64*SP f32 [c][p]
    float* h2n_out = h1n_out + F * SP;

    // workspace: 3 bf16 [p][c] buffers + weight fragments
    unsigned short* bufA = (unsigned short*)d_ws;         // SP*64 u16
    unsigned short* bufB = bufA + (size_t)SP * 64;
    unsigned short* hT   = bufB + (size_t)SP * 64;
    unsigned short* lru1_awp = hT + (size_t)SP * 64;      // 49152
    unsigned short* lru2_awp = lru1_awp + 49152;          // 49152
    unsigned short* wbt1_f   = lru2_awp + 49152;          // 36864
    unsigned short* wout1_f  = wbt1_f + 36864;            // 36864
    unsigned short* win2_f   = wout1_f + 36864;           // 12288
    unsigned short* wbt2_f   = win2_f + 12288;            // 12288
    unsigned short* win1_awp = wbt2_f + 12288;            // 4096

    const dim3 blk(256);
    const dim3 blk512(512);

    // 1) prep: all repacks + transpose h1 -> hT
    prep_all<<<dim3(784 + 1728), blk, 0, stream>>>(
        r1_wih, r1_whh, r2_wih, r2_whh, wbt_w1, wout_w1, win_w2, wbt_w2,
        win_w1, h1,
        lru1_awp, lru2_awp, wbt1_f, wout1_f, win2_f, wbt2_f, win1_awp, hT);

    // 2) fused win stage: x -> bufB
    fused_win<<<dim3(576), blk512, 0, stream>>>(
        x, win1_awp, win_b1, win2_f, win_b2, bufB);

    // 3) LRU 1: bufB,hT,h1 -> bufA, h1n
    lru_mfma10<<<dim3(1728), blk, 0, stream>>>(
        bufB, hT, h1, lru1_awp, r1_bih, r1_bh, bufA, h1n_out);

    // 4) fused wbt (bufA -> bufB) + transpose h2 -> hT rider
    fused_sp_tm_tr<<<dim3(576 + 1728), blk512, 0, stream>>>(
        bufA, wbt1_f, wbt_b1, wbt2_f, wbt_b2, bufB, h2, hT);

    // 5) LRU 2: bufB,hT,h2 -> bufA, h2n
    lru_mfma10<<<dim3(1728), blk, 0, stream>>>(
        bufB, hT, h2, lru2_awp, r2_bih, r2_bh, bufA, h2n_out);

    // 6) fused wout: bufA -> eta
    fused_sp_tmout<<<dim3(576), blk512, 0, stream>>>(
        bufA, wout1_f, wout_b1, wout_w2, wout_b2, eta_out);
}

// Round 21
// 182.950 us; speedup vs baseline: 1.0722x; 1.0031x over previous
//
#include <hip/hip_runtime.h>

#define TT 12
#define DD 96
#define WW 96
#define PLANE (DD*WW)      // 9216
#define SP (TT*PLANE)      // 110592
#define F 64

typedef short bf16x8 __attribute__((ext_vector_type(8)));
typedef short bf16x4 __attribute__((ext_vector_type(4)));
typedef float f32x4  __attribute__((ext_vector_type(4)));

__device__ __forceinline__ float sigmoidf_fast(float x){
    return 1.0f / (1.0f + __expf(-x));
}
// tanh = 1 - 2/(e^{2x}+1): 5 ops, clamp-free
__device__ __forceinline__ float tanhf_fast(float x){
    const float e = __expf(2.0f * x);
    return 1.0f - 2.0f / (e + 1.0f);
}
__device__ __forceinline__ unsigned short f2bf(float x){
    unsigned int u = __float_as_uint(x);
    u = (u + 0x7FFFu + ((u >> 16) & 1u)) >> 16;   // RNE
    return (unsigned short)u;
}
__device__ __forceinline__ float bf2f(unsigned short u){
    return __uint_as_float(((unsigned int)u) << 16);
}
__device__ __forceinline__ unsigned int cvt_pk_bf16(float lo, float hi){
    unsigned int r;
    asm("v_cvt_pk_bf16_f32 %0, %1, %2" : "=v"(r) : "v"(lo), "v"(hi));
    return r;
}

// ===========================================================================
// PREP: all weight repacks (200704 elems) + transpose h1 -> hT.
// blocks [0,784): repack flat; blocks [784, 784+1728): transpose tiles.
// ===========================================================================
__device__ __forceinline__ unsigned short repack_lru_elem(
    const float* wih, const float* whh, int idx)
{
    const int j    = idx & 7;
    const int lane = (idx >> 3) & 63;
    const int frag = idx >> 9;
    const int ks   = frag & 1;
    const int t    = (frag >> 1) % 12;
    const int fhi  = frag / 24;
    const int g    = (t < 6) ? t : t - 6;
    const int m    = g * 64 + fhi * 16 + (lane & 15);
    const int kk   = ks * 32 + (lane >> 4) * 8 + j;
    const float v  = (t < 6) ? wih[m * F + kk] : whh[m * F + kk];
    return f2bf(v);
}
__device__ __forceinline__ unsigned short repack_sp_elem(
    const float* wgt, int idx)
{
    const int j    = idx & 7;
    const int lane = (idx >> 3) & 63;
    const int frag = idx >> 9;
    const int fhi  = frag & 3;
    const int cl   = (frag >> 2) & 1;
    const int tap  = frag >> 3;
    const int f    = fhi * 16 + (lane & 15);
    const int c    = cl * 32 + (lane >> 4) * 8 + j;
    return f2bf(wgt[(f * 64 + c) * 9 + tap]);
}
__device__ __forceinline__ unsigned short repack_tm_elem(
    const float* wgt, int idx)
{
    const int j    = idx & 7;
    const int lane = (idx >> 3) & 63;
    const int frag = idx >> 9;
    const int fhi  = frag & 3;
    const int cl   = (frag >> 2) & 1;
    const int dt   = frag >> 3;
    const int f    = fhi * 16 + (lane & 15);
    const int c    = cl * 32 + (lane >> 4) * 8 + j;
    return f2bf(wgt[(f * 64 + c) * 3 + dt]);
}

__global__ __launch_bounds__(256) void prep_all(
    const float* __restrict__ r1_wih, const float* __restrict__ r1_whh,
    const float* __restrict__ r2_wih, const float* __restrict__ r2_whh,
    const float* __restrict__ wbt_w1, const float* __restrict__ wout_w1,
    const float* __restrict__ win_w2, const float* __restrict__ wbt_w2,
    const float* __restrict__ win_w1, const float* __restrict__ h1,
    unsigned short* __restrict__ lru1_awp, unsigned short* __restrict__ lru2_awp,
    unsigned short* __restrict__ wbt1_f, unsigned short* __restrict__ wout1_f,
    unsigned short* __restrict__ win2_f, unsigned short* __restrict__ wbt2_f,
    unsigned short* __restrict__ win1_awp, unsigned short* __restrict__ hT)
{
    __shared__ float tile[64 * 65];
    const int bx = blockIdx.x;
    if (bx < 784) {
        const int idx = bx * 256 + threadIdx.x;
        if (idx < 49152) {
            lru1_awp[idx] = repack_lru_elem(r1_wih, r1_whh, idx);
        } else if (idx < 98304) {
            const int i = idx - 49152;
            lru2_awp[i] = repack_lru_elem(r2_wih, r2_whh, i);
        } else if (idx < 135168) {
            const int i = idx - 98304;
            wbt1_f[i] = repack_sp_elem(wbt_w1, i);
        } else if (idx < 172032) {
            const int i = idx - 135168;
            wout1_f[i] = repack_sp_elem(wout_w1, i);
        } else if (idx < 184320) {
            const int i = idx - 172032;
            win2_f[i] = repack_tm_elem(win_w2, i);
        } else if (idx < 196608) {
            const int i = idx - 184320;
            wbt2_f[i] = repack_tm_elem(wbt_w2, i);
        } else if (idx < 200704) {
            // win1 im2col A-frags: frag = fhi*2+ks; k = c*16+tap (tap 9..15 pad 0)
            const int i    = idx - 196608;
            const int j    = i & 7;
            const int lane = (i >> 3) & 63;
            const int frag = i >> 9;          // 0..7
            const int ks   = frag & 1;
            const int fhi  = frag >> 1;
            const int m    = fhi * 16 + (lane & 15);
            const int kk   = ks * 32 + (lane >> 4) * 8 + j;
            const int c    = kk >> 4;
            const int tp   = kk & 15;
            win1_awp[i] = (tp < 9) ? f2bf(win_w1[(m * 4 + c) * 9 + tp])
                                   : (unsigned short)0;
        }
    } else {
        // transpose h1 tile (256 threads)
        const int tid  = threadIdx.x;
        const int wv   = tid >> 6;
        const int lane = tid & 63;
        const int p0   = (bx - 784) * 64;
        #pragma unroll
        for (int cc = 0; cc < 16; cc++) {
            const int c = cc * 4 + wv;
            tile[lane * 65 + c] = h1[(size_t)c * SP + p0 + lane];
        }
        __syncthreads();
        #pragma unroll
        for (int k = 0; k < 2; k++) {
            const int p  = (tid >> 3) + k * 32;
            const int c0 = (tid & 7) * 8;
            bf16x8 v;
            #pragma unroll
            for (int i = 0; i < 8; i++)
                v[i] = (short)f2bf(tile[p * 65 + c0 + i]);
            *(bf16x8*)(hT + (size_t)(p0 + p) * 64 + c0) = v;
        }
    }
}

// ===========================================================================
// FUSED win stage: im2col MFMA spatial conv (CIN=4, K=64 padded) -> LDS
// (swizzled bf16) -> temporal tm MFMA (weights LDS-staged) -> bufB.
// ===========================================================================
__global__ __launch_bounds__(512, 4) void fused_win(
    const float* __restrict__ x,
    const unsigned short* __restrict__ awp1, const float* __restrict__ bias1,
    const unsigned short* __restrict__ afr_tm, const float* __restrict__ bias_tm,
    unsigned short* __restrict__ out)
{
    __shared__ unsigned short y[8 * 2048];     // 32 KB
    __shared__ unsigned short wbuf[12288];     // 24 KB
    const int tid  = threadIdx.x;
    const int wv   = tid >> 6;
    const int lane = tid & 63;
    const int col  = lane & 15;
    const int kg   = lane >> 4;
    const int bx   = blockIdx.x;             // 0..575
    const int th   = bx / 288;
    const int rem  = bx - th * 288;
    const int d    = rem / 3;
    const int wseg = rem - d * 3;
    const int w0   = wseg * 32;
    const int t0   = th * 6;
    const int tsrc = (t0 + wv + 11) % 12;

    // stage tm weight table (24 KB) early -- used in phase B
    {
        const uint4* src = (const uint4*)afr_tm;
        uint4* dst = (uint4*)wbuf;
        #pragma unroll
        for (int i = 0; i < 3; i++)
            dst[i * 512 + tid] = src[i * 512 + tid];
    }

    // ---- phase A: spatial conv via im2col MFMA ----
    const int kgodd = kg & 1;
    const int c_lo  = kg >> 1;
    int wn[2];
    wn[0] = w0 + col;
    wn[1] = w0 + 16 + col;

    bf16x8 bf[2][2];
    const float* xb = x + (size_t)tsrc * PLANE;
    #pragma unroll
    for (int ks = 0; ks < 2; ks++) {
        const int c = ks * 2 + c_lo;
        const float* xc = xb + (size_t)c * SP;
        #pragma unroll
        for (int nt = 0; nt < 2; nt++) {
            bf16x8 v;
            #pragma unroll
            for (int j = 0; j < 8; j++) v[j] = 0;
            if (!kgodd) {
                #pragma unroll
                for (int j = 0; j < 8; j++) {   // tp = j = ddi*3+dwi
                    const int ddi = j / 3, dwi = j % 3;
                    const int dr = min(max(d + ddi - 1, 0), DD - 1);
                    const int wc = min(max(wn[nt] + dwi - 1, 0), WW - 1);
                    v[j] = (short)f2bf(xc[dr * WW + wc]);
                }
            } else {                             // tp = 8: ddi=2, dwi=2
                const int dr = min(d + 1, DD - 1);
                const int wc = min(wn[nt] + 1, WW - 1);
                v[0] = (short)f2bf(xc[dr * WW + wc]);
            }
            bf[ks][nt] = v;
        }
    }

    f32x4 acc[4][2];
    #pragma unroll
    for (int fhi = 0; fhi < 4; fhi++)
        #pragma unroll
        for (int nt = 0; nt < 2; nt++)
            acc[fhi][nt] = (f32x4){0.f, 0.f, 0.f, 0.f};

    #pragma unroll
    for (int ks = 0; ks < 2; ks++) {
        #pragma unroll
        for (int fhi = 0; fhi < 4; fhi++) {
            const bf16x8 a = *(const bf16x8*)(awp1 + (size_t)(fhi * 2 + ks) * 512 + lane * 8);
            acc[fhi][0] = __builtin_amdgcn_mfma_f32_16x16x32_bf16(a, bf[ks][0], acc[fhi][0], 0, 0, 0);
            acc[fhi][1] = __builtin_amdgcn_mfma_f32_16x16x32_bf16(a, bf[ks][1], acc[fhi][1], 0, 0, 0);
        }
    }

    // epilogue -> LDS (swizzled), bias + relu
    #pragma unroll
    for (int fhi = 0; fhi < 4; fhi++) {
        const float4 bv = *(const float4*)(bias1 + fhi * 16 + kg * 4);
        const int f0 = fhi * 16 + kg * 4;
        #pragma unroll
        for (int nt = 0; nt < 2; nt++) {
            const int pl = nt * 16 + col;
            const unsigned int lo = cvt_pk_bf16(fmaxf(acc[fhi][nt][0] + bv.x, 0.f),
                                                fmaxf(acc[fhi][nt][1] + bv.y, 0.f));
            const unsigned int hi = cvt_pk_bf16(fmaxf(acc[fhi][nt][2] + bv.z, 0.f),
                                                fmaxf(acc[fhi][nt][3] + bv.w, 0.f));
            const int idx = wv * 2048 + pl * 64 + (f0 ^ ((pl & 7) << 3));
            *(uint2*)(y + idx) = make_uint2(lo, hi);
        }
    }

    __syncthreads();

    // ---- phase B: temporal conv (waves 0..5), weights from wbuf ----
    if (wv < 6) {
        f32x4 acc2[4][2];
        #pragma unroll
        for (int fhi = 0; fhi < 4; fhi++)
            #pragma unroll
            for (int nt = 0; nt < 2; nt++)
                acc2[fhi][nt] = (f32x4){0.f, 0.f, 0.f, 0.f};

        const int cswz = (col & 7) << 3;
        const int lane8 = lane * 8;
        #pragma unroll
        for (int dt = 0; dt < 3; dt++) {
            const unsigned short* yb = y + (wv + dt) * 2048;
            #pragma unroll
            for (int cl = 0; cl < 2; cl++) {
                const int coff = (cl * 32 + kg * 8) ^ cswz;
                const bf16x8 b0 = *(const bf16x8*)(yb + col * 64 + coff);
                const bf16x8 b1 = *(const bf16x8*)(yb + (col + 16) * 64 + coff);
                const unsigned short* ap = wbuf + ((dt * 2 + cl) * 4) * 512 + lane8;
                #pragma unroll
                for (int fhi = 0; fhi < 4; fhi++) {
                    const bf16x8 a = *(const bf16x8*)(ap + fhi * 512);
                    acc2[fhi][0] = __builtin_amdgcn_mfma_f32_16x16x32_bf16(a, b0, acc2[fhi][0], 0, 0, 0);
                    acc2[fhi][1] = __builtin_amdgcn_mfma_f32_16x16x32_bf16(a, b1, acc2[fhi][1], 0, 0, 0);
                }
            }
        }

        const int pbase = (t0 + wv) * PLANE + d * WW + w0;
        #pragma unroll
        for (int fhi = 0; fhi < 4; fhi++) {
            const float4 bv = *(const float4*)(bias_tm + fhi * 16 + kg * 4);
            #pragma unroll
            for (int nt = 0; nt < 2; nt++) {
                const int p = pbase + nt * 16 + col;
                const unsigned int lo = cvt_pk_bf16(fmaxf(acc2[fhi][nt][0] + bv.x, 0.f),
                                                    fmaxf(acc2[fhi][nt][1] + bv.y, 0.f));
                const unsigned int hi = cvt_pk_bf16(fmaxf(acc2[fhi][nt][2] + bv.z, 0.f),
                                                    fmaxf(acc2[fhi][nt][3] + bv.w, 0.f));
                *(uint2*)(out + (size_t)p * 64 + fhi * 16 + kg * 4) = make_uint2(lo, hi);
            }
        }
    }
}

// ===========================================================================
// Shared phase A for the 64-channel spatial conv (wbt/wout), MFMA, -> LDS.
// Round-21: each ddi-row's 12 input b128 loads are ISSUED BEFORE the staging
// barrier pair -- the barrier's mandatory vmcnt drain absorbs their latency
// (other waves stage/compute meanwhile), so the post-barrier MFMA chain
// starts with operands in registers. Pure reorder vs round 20.
// Must be called by ALL threads of the block (contains barriers).
// ===========================================================================
__device__ __forceinline__ void fused_phaseA_sp(
    const unsigned short* __restrict__ in,
    const unsigned short* __restrict__ afr_sp, const float* __restrict__ bias_sp,
    unsigned short* __restrict__ y, unsigned short* __restrict__ wbuf,
    int tid, int wv, int col, int kg, int d, int w0, int t)
{
    int wn[2];
    wn[0] = w0 + col;
    wn[1] = w0 + 16 + col;
    int voff[2][3];
    #pragma unroll
    for (int nt = 0; nt < 2; nt++)
        #pragma unroll
        for (int dwi = 0; dwi < 3; dwi++) {
            int wc = wn[nt] + dwi - 1;
            wc = min(max(wc, 0), WW - 1);
            voff[nt][dwi] = wc * 64 + kg * 8;
        }

    f32x4 acc[4][2];
    #pragma unroll
    for (int fhi = 0; fhi < 4; fhi++)
        #pragma unroll
        for (int nt = 0; nt < 2; nt++)
            acc[fhi][nt] = (f32x4){0.f, 0.f, 0.f, 0.f};

    const int tb = t * PLANE;
    const int lane8 = (kg * 16 + col) * 8;
    #pragma unroll
    for (int ddi = 0; ddi < 3; ddi++) {
        int dr = d + ddi - 1;
        dr = min(max(dr, 0), DD - 1);
        const unsigned short* rp = in + (size_t)(tb + dr * WW) * 64;

        // issue this row's data loads BEFORE the barrier pair: the barrier
        // drain overlaps their latency with other waves' staging.
        bf16x8 row[3][2][2];   // [dwi][cl][nt]
        #pragma unroll
        for (int dwi = 0; dwi < 3; dwi++)
            #pragma unroll
            for (int cl = 0; cl < 2; cl++) {
                row[dwi][cl][0] = *(const bf16x8*)(rp + voff[0][dwi] + cl * 32);
                row[dwi][cl][1] = *(const bf16x8*)(rp + voff[1][dwi] + cl * 32);
            }

        __syncthreads();   // previous row's wbuf reads complete
        {
            const uint4* src = (const uint4*)(afr_sp + (size_t)ddi * 12288);
            uint4* dst = (uint4*)wbuf;
            #pragma unroll
            for (int i = 0; i < 3; i++)
                dst[i * 512 + tid] = src[i * 512 + tid];
        }
        __syncthreads();

        #pragma unroll
        for (int dwi = 0; dwi < 3; dwi++) {
            #pragma unroll
            for (int cl = 0; cl < 2; cl++) {
                const unsigned short* ap = wbuf + ((dwi * 2 + cl) * 4) * 512 + lane8;
                #pragma unroll
                for (int fhi = 0; fhi < 4; fhi++) {
                    const bf16x8 a = *(const bf16x8*)(ap + fhi * 512);
                    acc[fhi][0] = __builtin_amdgcn_mfma_f32_16x16x32_bf16(a, row[dwi][cl][0], acc[fhi][0], 0, 0, 0);
                    acc[fhi][1] = __builtin_amdgcn_mfma_f32_16x16x32_bf16(a, row[dwi][cl][1], acc[fhi][1], 0, 0, 0);
                }
            }
        }
    }

    #pragma unroll
    for (int fhi = 0; fhi < 4; fhi++) {
        const float4 bv = *(const float4*)(bias_sp + fhi * 16 + kg * 4);
        const int f0 = fhi * 16 + kg * 4;
        #pragma unroll
        for (int nt = 0; nt < 2; nt++) {
            const int pl = nt * 16 + col;
            const unsigned int lo = cvt_pk_bf16(fmaxf(acc[fhi][nt][0] + bv.x, 0.f),
                                                fmaxf(acc[fhi][nt][1] + bv.y, 0.f));
            const unsigned int hi = cvt_pk_bf16(fmaxf(acc[fhi][nt][2] + bv.z, 0.f),
                                                fmaxf(acc[fhi][nt][3] + bv.w, 0.f));
            const int idx = wv * 2048 + pl * 64 + (f0 ^ ((pl & 7) << 3));
            *(uint2*)(y + idx) = make_uint2(lo, hi);
        }
    }
}

// ===========================================================================
// FUSED wbt: spatial->LDS->temporal (blocks <576) + transpose h2 rider
// (blocks >=576, reuses hT which is dead after lru1).
// ===========================================================================
__global__ __launch_bounds__(512, 4) void fused_sp_tm_tr(
    const unsigned short* __restrict__ in,
    const unsigned short* __restrict__ afr_sp, const float* __restrict__ bias_sp,
    const unsigned short* __restrict__ afr_tm, const float* __restrict__ bias_tm,
    unsigned short* __restrict__ out,
    const float* __restrict__ h2, unsigned short* __restrict__ hT)
{
    __shared__ unsigned short y[8 * 2048];     // 32 KB (aliased by transpose)
    __shared__ unsigned short wbuf[12288];     // 24 KB weight staging
    const int tid  = threadIdx.x;
    const int wv   = tid >> 6;
    const int lane = tid & 63;
    const int bx   = blockIdx.x;

    if (bx >= 576) {
        // ---- transpose h2 tile: f32 [c][p] -> bf16 [p][c] ----
        float* tile = (float*)y;             // 64*65*4 = 16.6 KB < 32 KB
        const int p0 = (bx - 576) * 64;
        #pragma unroll
        for (int cc = 0; cc < 8; cc++) {
            const int c = cc * 8 + wv;
            tile[lane * 65 + c] = h2[(size_t)c * SP + p0 + lane];
        }
        __syncthreads();
        const int p  = tid >> 3;
        const int c0 = (tid & 7) * 8;
        bf16x8 v;
        #pragma unroll
        for (int i = 0; i < 8; i++)
            v[i] = (short)f2bf(tile[p * 65 + c0 + i]);
        *(bf16x8*)(hT + (size_t)(p0 + p) * 64 + c0) = v;
        return;
    }

    const int col  = lane & 15;
    const int kg   = lane >> 4;
    const int th   = bx / 288;
    const int rem  = bx - th * 288;
    const int d    = rem / 3;
    const int wseg = rem - d * 3;
    const int w0   = wseg * 32;
    const int t0   = th * 6;

    fused_phaseA_sp(in, afr_sp, bias_sp, y, wbuf, tid, wv, col, kg, d, w0,
                    (t0 + wv + 11) % 12);

    // restage wbuf with tm table; barrier also publishes y
    __syncthreads();
    {
        const uint4* src = (const uint4*)afr_tm;
        uint4* dst = (uint4*)wbuf;
        #pragma unroll
        for (int i = 0; i < 3; i++)
            dst[i * 512 + tid] = src[i * 512 + tid];
    }
    __syncthreads();

    if (wv < 6) {
        f32x4 acc[4][2];
        #pragma unroll
        for (int fhi = 0; fhi < 4; fhi++)
            #pragma unroll
            for (int nt = 0; nt < 2; nt++)
                acc[fhi][nt] = (f32x4){0.f, 0.f, 0.f, 0.f};

        const int cswz = (col & 7) << 3;
        const int lane8 = lane * 8;
        #pragma unroll
        for (int dt = 0; dt < 3; dt++) {
            const unsigned short* yb = y + (wv + dt) * 2048;
            #pragma unroll
            for (int cl = 0; cl < 2; cl++) {
                const int coff = (cl * 32 + kg * 8) ^ cswz;
                const bf16x8 b0 = *(const bf16x8*)(yb + col * 64 + coff);
                const bf16x8 b1 = *(const bf16x8*)(yb + (col + 16) * 64 + coff);
                const unsigned short* ap = wbuf + ((dt * 2 + cl) * 4) * 512 + lane8;
                #pragma unroll
                for (int fhi = 0; fhi < 4; fhi++) {
                    const bf16x8 a = *(const bf16x8*)(ap + fhi * 512);
                    acc[fhi][0] = __builtin_amdgcn_mfma_f32_16x16x32_bf16(a, b0, acc[fhi][0], 0, 0, 0);
                    acc[fhi][1] = __builtin_amdgcn_mfma_f32_16x16x32_bf16(a, b1, acc[fhi][1], 0, 0, 0);
                }
            }
        }

        const int pbase = (t0 + wv) * PLANE + d * WW + w0;
        #pragma unroll
        for (int fhi = 0; fhi < 4; fhi++) {
            const float4 bv = *(const float4*)(bias_tm + fhi * 16 + kg * 4);
            #pragma unroll
            for (int nt = 0; nt < 2; nt++) {
                const int p = pbase + nt * 16 + col;
                const unsigned int lo = cvt_pk_bf16(fmaxf(acc[fhi][nt][0] + bv.x, 0.f),
                                                    fmaxf(acc[fhi][nt][1] + bv.y, 0.f));
                const unsigned int hi = cvt_pk_bf16(fmaxf(acc[fhi][nt][2] + bv.z, 0.f),
                                                    fmaxf(acc[fhi][nt][3] + bv.w, 0.f));
                *(uint2*)(out + (size_t)p * 64 + fhi * 16 + kg * 4) = make_uint2(lo, hi);
            }
        }
    }
}

// ===========================================================================
// FUSED wout: spatial->LDS->final temporal (COUT=2, no relu, f32 out).
// ===========================================================================
__global__ __launch_bounds__(512, 4) void fused_sp_tmout(
    const unsigned short* __restrict__ in,
    const unsigned short* __restrict__ afr_sp, const float* __restrict__ bias_sp,
    const float* __restrict__ wgt, const float* __restrict__ bias_out,
    float* __restrict__ out)
{
    __shared__ unsigned short y[8 * 2048];     // 32 KB
    __shared__ unsigned short wbuf[12288];     // 24 KB weight staging
    const int tid  = threadIdx.x;
    const int wv   = tid >> 6;
    const int lane = tid & 63;
    const int col  = lane & 15;
    const int kg   = lane >> 4;
    const int bx   = blockIdx.x;
    const int th   = bx / 288;
    const int rem  = bx - th * 288;
    const int d    = rem / 3;
    const int wseg = rem - d * 3;
    const int w0   = wseg * 32;
    const int t0   = th * 6;

    fused_phaseA_sp(in, afr_sp, bias_sp, y, wbuf, tid, wv, col, kg, d, w0,
                    (t0 + wv + 11) % 12);
    __syncthreads();

    if (tid < 384) {
        const int pl = tid & 31;
        const int tv = (tid >> 5) % 6;
        const int ch = tid / 192;            // wave-uniform
        const int cswz = (pl & 7) << 3;
        float acc = 0.f;
        #pragma unroll
        for (int c0 = 0; c0 < 64; c0 += 8) {
            const int coff = pl * 64 + (c0 ^ cswz);
            const bf16x8 vm = *(const bf16x8*)(y + (tv    ) * 2048 + coff);
            const bf16x8 vc = *(const bf16x8*)(y + (tv + 1) * 2048 + coff);
            const bf16x8 vp = *(const bf16x8*)(y + (tv + 2) * 2048 + coff);
            #pragma unroll
            for (int jj = 0; jj < 8; jj++) {
                const int c = c0 + jj;
                const float* wq = wgt + (ch * 64 + c) * 3;
                acc += bf2f((unsigned short)vm[jj]) * wq[0]
                     + bf2f((unsigned short)vc[jj]) * wq[1]
                     + bf2f((unsigned short)vp[jj]) * wq[2];
            }
        }
        const int p = (t0 + tv) * PLANE + d * WW + w0 + pl;
        out[ch * SP + p] = acc + bias_out[ch];
    }
}

// ===========================================================================
// LRU via MFMA, v10 (round-20 best): nt-INNER MFMA loop; each A-fragment
// ds_read ONCE, used by both nt-columns. Block = 4 waves x 32 pos, one fhi
// pair; grid 1728; 48 KB LDS.
// ===========================================================================
__global__ __launch_bounds__(256, 1) void lru_mfma10(
    const unsigned short* __restrict__ x, const unsigned short* __restrict__ hT,
    const float* __restrict__ h,
    const unsigned short* __restrict__ awp,
    const float* __restrict__ bih, const float* __restrict__ bh,
    unsigned short* __restrict__ out, float* __restrict__ hnew)
{
    __shared__ unsigned short sA[24576];   // 48 KB: awp slice for fhi pair
    const int tid  = threadIdx.x;
    const int wave = tid >> 6;
    const int lane = tid & 63;
    const int col  = lane & 15;
    const int kg   = lane >> 4;
    const int bid  = blockIdx.x;           // 0..1727
    const int fp   = (bid & 1) * 2;        // fhi pair base
    const int p0   = (bid >> 1) * 128 + wave * 32;

    {
        const uint4* src = (const uint4*)(awp + (size_t)fp * 12288);
        uint4* dst = (uint4*)sA;
        #pragma unroll
        for (int i = 0; i < 12; i++)
            dst[i * 256 + tid] = src[i * 256 + tid];
    }

    bf16x8 bx[2][2], bh8[2][2];
    #pragma unroll
    for (int nt = 0; nt < 2; nt++) {
        const size_t pb = (size_t)(p0 + nt * 16 + col) * 64 + kg * 8;
        #pragma unroll
        for (int ks = 0; ks < 2; ks++) {
            bx[ks][nt]  = *(const bf16x8*)(x  + pb + ks * 32);
            bh8[ks][nt] = *(const bf16x8*)(hT + pb + ks * 32);
        }
    }

    __syncthreads();

    #pragma unroll
    for (int ff = 0; ff < 2; ff++) {
        const int fhi  = fp + ff;
        const int f0   = fhi * 16 + kg * 4;
        const int fcol = fhi * 16 + col;
        const unsigned short* ap = sA + ff * 12288 + lane * 8;

        const float4 b0v = *(const float4*)(bih + 0*F + f0);
        const float4 b2v = *(const float4*)(bih + 2*F + f0);
        const float4 b4v = *(const float4*)(bih + 4*F + f0);
        const float b0a[4] = {b0v.x, b0v.y, b0v.z, b0v.w};
        const float b2a[4] = {b2v.x, b2v.y, b2v.z, b2v.w};
        const float b4a[4] = {b4v.x, b4v.y, b4v.z, b4v.w};
        const float bih1f = bih[1*F + fcol];
        const float bih3f = bih[3*F + fcol];
        const float bih5f = bih[5*F + fcol];
        const float bhf   = bh[fcol];

        // epilogue operands issued early (hide under MFMAs)
        bf16x4 xv4[2];
        float4 h4[2];
        #pragma unroll
        for (int nt = 0; nt < 2; nt++) {
            const int p    = p0 + nt * 16 + col;
            const int prow = p0 + nt * 16 + kg * 4;
            xv4[nt] = *(const bf16x4*)(x + (size_t)p * 64 + f0);
            h4[nt]  = *(const float4*)(h + (size_t)fcol * SP + prow);
        }

        // both nt accumulator sets live; each frag ds_read ONCE, used twice
        f32x4 aco0[6], aco1[6], ach0[6], ach1[6];
        #pragma unroll
        for (int j = 0; j < 6; j++) {
            aco0[j] = (f32x4){0.f, 0.f, 0.f, 0.f};
            aco1[j] = (f32x4){0.f, 0.f, 0.f, 0.f};
            ach0[j] = (f32x4){0.f, 0.f, 0.f, 0.f};
            ach1[j] = (f32x4){0.f, 0.f, 0.f, 0.f};
        }

        #pragma unroll
        for (int t = 0; t < 12; t++) {
            const int j = t >> 1;
            #pragma unroll
            for (int ks = 0; ks < 2; ks++) {
                const bf16x8 a = *(const bf16x8*)(ap + (t * 2 + ks) * 512);
                const bf16x8 d0 = (t < 6) ? bx[ks][0] : bh8[ks][0];
                const bf16x8 d1 = (t < 6) ? bx[ks][1] : bh8[ks][1];
                if ((t & 1) == 0) {
                    aco0[j] = __builtin_amdgcn_mfma_f32_16x16x32_bf16(a, d0, aco0[j], 0, 0, 0);
                    aco1[j] = __builtin_amdgcn_mfma_f32_16x16x32_bf16(a, d1, aco1[j], 0, 0, 0);
                } else {
                    ach0[j] = __builtin_amdgcn_mfma_f32_16x16x32_bf16(d0, a, ach0[j], 0, 0, 0);
                    ach1[j] = __builtin_amdgcn_mfma_f32_16x16x32_bf16(d1, a, ach1[j], 0, 0, 0);
                }
            }
        }

        #pragma unroll
        for (int nt = 0; nt < 2; nt++) {
            const int p    = p0 + nt * 16 + col;
            const int prow = p0 + nt * 16 + kg * 4;
            const f32x4* aco = nt ? aco1 : aco0;
            const f32x4* ach = nt ? ach1 : ach0;

            float o[4];
            #pragma unroll
            for (int r = 0; r < 4; r++) {
                const float ri = sigmoidf_fast(aco[0][r] + b0a[r] + aco[3][r]);
                const float zi = sigmoidf_fast(aco[1][r] + b2a[r] + aco[4][r]);
                const float ch = tanhf_fast(ri * (aco[2][r] + b4a[r]) + aco[5][r]);
                const float xf = bf2f((unsigned short)xv4[nt][r]);
                o[r] = fmaf(zi, ch - xf, xf);
            }
            *(uint2*)(out + (size_t)p * 64 + f0) =
                make_uint2(cvt_pk_bf16(o[0], o[1]), cvt_pk_bf16(o[2], o[3]));

            const float hsrc[4] = {h4[nt].x, h4[nt].y, h4[nt].z, h4[nt].w};
            float hnr[4];
            #pragma unroll
            for (int r = 0; r < 4; r++) {
                const float rh = sigmoidf_fast(ach[0][r] + bih1f + ach[3][r]);
                const float zh = sigmoidf_fast(ach[1][r] + bih3f + ach[4][r]);
                const float ci = tanhf_fast(ach[2][r] + bih5f + rh * (ach[5][r] + bhf));
                hnr[r] = fmaf(zh, ci - hsrc[r], hsrc[r]);
            }
            float4 hn;
            hn.x = hnr[0]; hn.y = hnr[1]; hn.z = hnr[2]; hn.w = hnr[3];
            *(float4*)(hnew + (size_t)fcol * SP + prow) = hn;
        }
    }
}

// ===========================================================================
extern "C" void kernel_launch(void* const* d_in, const int* in_sizes, int n_in,
                              void* d_out, int out_size, void* d_ws, size_t ws_size,
                              hipStream_t stream) {
    const float* x       = (const float*)d_in[0];
    const float* h1      = (const float*)d_in[1];
    const float* h2      = (const float*)d_in[2];
    const float* win_w1  = (const float*)d_in[3];
    const float* win_b1  = (const float*)d_in[4];
    const float* win_w2  = (const float*)d_in[5];
    const float* win_b2  = (const float*)d_in[6];
    const float* r1_wih  = (const float*)d_in[7];
    const float* r1_bih  = (const float*)d_in[8];
    const float* r1_whh  = (const float*)d_in[9];
    const float* r1_bh   = (const float*)d_in[10];
    const float* wbt_w1  = (const float*)d_in[11];
    const float* wbt_b1  = (const float*)d_in[12];
    const float* wbt_w2  = (const float*)d_in[13];
    const float* wbt_b2  = (const float*)d_in[14];
    const float* r2_wih  = (const float*)d_in[15];
    const float* r2_bih  = (const float*)d_in[16];
    const float* r2_whh  = (const float*)d_in[17];
    const float* r2_bh   = (const float*)d_in[18];
    const float* wout_w1 = (const float*)d_in[19];
    const float* wout_b1 = (const float*)d_in[20];
    const float* wout_w2 = (const float*)d_in[21];
    const float* wout_b2 = (const float*)d_in[22];

    float* eta_out = (float*)d_out;                       // 2*SP
    float* h1n_out = eta_out + 2 * SP;                    // 64*SP f32 [c][p]
    float* h2n_out = h1n_out + F * SP;

    // workspace: 3 bf16 [p][c] buffers + weight fragments
    unsigned short* bufA = (unsigned short*)d_ws;         // SP*64 u16
    unsigned short* bufB = bufA + (size_t)SP * 64;
    unsigned short* hT   = bufB + (size_t)SP * 64;
    unsigned short* lru1_awp = hT + (size_t)SP * 64;      // 49152
    unsigned short* lru2_awp = lru1_awp + 49152;          // 49152
    unsigned short* wbt1_f   = lru2_awp + 49152;          // 36864
    unsigned short* wout1_f  = wbt1_f + 36864;            // 36864
    unsigned short* win2_f   = wout1_f + 36864;           // 12288
    unsigned short* wbt2_f   = win2_f + 12288;            // 12288
    unsigned short* win1_awp = wbt2_f + 12288;            // 4096

    const dim3 blk(256);
    const dim3 blk512(512);

    // 1) prep: all repacks + transpose h1 -> hT
    prep_all<<<dim3(784 + 1728), blk, 0, stream>>>(
        r1_wih, r1_whh, r2_wih, r2_whh, wbt_w1, wout_w1, win_w2, wbt_w2,
        win_w1, h1,
        lru1_awp, lru2_awp, wbt1_f, wout1_f, win2_f, wbt2_f, win1_awp, hT);

    // 2) fused win stage: x -> bufB
    fused_win<<<dim3(576), blk512, 0, stream>>>(
        x, win1_awp, win_b1, win2_f, win_b2, bufB);

    // 3) LRU 1: bufB,hT,h1 -> bufA, h1n
    lru_mfma10<<<dim3(1728), blk, 0, stream>>>(
        bufB, hT, h1, lru1_awp, r1_bih, r1_bh, bufA, h1n_out);

    // 4) fused wbt (bufA -> bufB) + transpose h2 -> hT rider
    fused_sp_tm_tr<<<dim3(576 + 1728), blk512, 0, stream>>>(
        bufA, wbt1_f, wbt_b1, wbt2_f, wbt_b2, bufB, h2, hT);

    // 5) LRU 2: bufB,hT,h2 -> bufA, h2n
    lru_mfma10<<<dim3(1728), blk, 0, stream>>>(
        bufB, hT, h2, lru2_awp, r2_bih, r2_bh, bufA, h2n_out);

    // 6) fused wout: bufA -> eta
    fused_sp_tmout<<<dim3(576), blk512, 0, stream>>>(
        bufA, wout1_f, wout_b1, wout_w2, wout_b2, eta_out);
}